// Round 1
// 1278.984 us; speedup vs baseline: 1.0566x; 1.0566x over previous
//
#include <hip/hip_runtime.h>
#include <cstdint>
#include <cstddef>

// ---------------- constants ----------------
#define KB   8
#define KS   512
#define KD   1024
#define KH   16
#define KDH  64
#define KE   8
#define KDFF 4096
#define KN   4096      // B*S tokens
#define KCAP 1280      // ceil(2*4096/8*1.25)
#define KCHB 32        // attention bh per chunk
#define KNCH 4         // 128 / KCHB
#define KPLE ((long)KN*KD)   // plane elements

typedef unsigned short u16;
typedef _Float16 f16;
typedef f16   f16x8 __attribute__((ext_vector_type(8)));
typedef float f32x4 __attribute__((ext_vector_type(4)));

#define RSCALE 4096.0f
#define RINV   2.44140625e-4f   // 1/4096

__device__ __forceinline__ u16 f2h(float f){
  f16 h = (f16)f;
  return __builtin_bit_cast(u16, h);
}
__device__ __forceinline__ float h2f(u16 u){
  f16 h = __builtin_bit_cast(f16, u);
  return (float)h;
}
// 2-plane f16 split; residual plane pre-scaled x4096 so it stays in f16
// normal range (guards against possible MFMA denorm-input flush).
__device__ __forceinline__ void split2v(float f, u16 &a, u16 &b){
  f16 h0 = (f16)f;
  float r = (f - (float)h0) * RSCALE;
  a = __builtin_bit_cast(u16, h0);
  b = f2h(r);
}
__device__ __forceinline__ f16x8 ld8h(const u16* p){
  uint4 v = *(const uint4*)p;
  return __builtin_bit_cast(f16x8, v);
}
// async global->LDS, 16B per lane; lds ptr must be wave-uniform (HW adds lane*16)
__device__ __forceinline__ void async16(const u16* g, u16* l){
  __builtin_amdgcn_global_load_lds(
      (const __attribute__((address_space(1))) unsigned int*)(g),
      (__attribute__((address_space(3))) unsigned int*)(l),
      16, 0, 0);
}

// bijective XCD-aware remap (m204): dispatch id -> work id so each XCD
// gets a contiguous chunk of the grid (per-XCD L2 locality).
__device__ __forceinline__ int xcd_remap(int lin, int nwg){
  int qq = nwg >> 3, r8 = nwg & 7;
  int xcd = lin & 7, pos = lin >> 3;
  return (xcd < r8 ? xcd*(qq+1) : r8*(qq+1) + (xcd-r8)*qq) + pos;
}

struct GArgs {
  const u16 *A0, *A1;
  const u16 *B0, *B1;
  long lda, sA, ldb, sB;         // element strides
  const float* bias; long biasStride;
  float* outF;
  u16 *o0;
  u16 *o1;                       // mode 7: V token-plane base
  int K, mode;
  int hbase;                     // mode 2: chunk base bh
  float scale;
};

// ---------------- 128x128 4-wave GEMM, LDS staged via global_load_lds ----------
// NP=2: A,B are (main, residual*4096) f16 planes; 3-term product ~ fp32 accuracy.
// LDS per plane: 128 rows x 32 cols f16, chunk-slot XOR swizzle (conflict-free, R2 PMC).
template<int NP>
__launch_bounds__(256)
__global__ void gemm128(GArgs g){
  __shared__ __align__(16) u16 sm[NP*2*4096];
  const int tid  = threadIdx.x;
  const int lane = tid & 63;
  const int wave = tid >> 6;
  const int quad = lane >> 4;
  const int r    = lane & 15;
  const int wm = (wave & 1) * 64;
  const int wn = (wave >> 1) * 64;
  // XCD-aware block remap (all grids here are multiples of 8)
  const int gx = gridDim.x, gy = gridDim.y;
  const int nwg = gx*gy*(int)gridDim.z;
  int lin = (int)blockIdx.x + gx*((int)blockIdx.y + gy*(int)blockIdx.z);
  lin = xcd_remap(lin, nwg);
  const int bx = lin % gx;
  const int byy = (lin / gx) % gy;
  const int z  = lin / (gx*gy);
  const long m0 = (long)byy * 128;
  const long n0 = (long)bx * 128;
  const u16* Ap[NP]; const u16* Bp[NP];
  if (g.mode == 2){
    // token-layout heads: offset = (b)*KS*KD + h*KDH
    int bh = g.hbase + z;
    long off = ((long)(bh >> 4)*KS)*KD + (long)(bh & 15)*KDH;
    Ap[0] = g.A0 + off; Bp[0] = g.B0 + off;
    if (NP == 2){ Ap[1] = g.A1 + off; Bp[1] = g.B1 + off; }
  } else {
    Ap[0] = g.A0 + (long)z*g.sA; Bp[0] = g.B0 + (long)z*g.sB;
    if (NP == 2){ Ap[1] = g.A1 + (long)z*g.sA; Bp[1] = g.B1 + (long)z*g.sB; }
  }
  const int srow   = tid >> 2;
  const int schunk = (tid & 3) ^ ((tid >> 3) & 3);
  f32x4 acc[4][4] = {};
  f32x4 accr[4][4] = {};          // cross-term accumulator (NP==2 only; elided otherwise)
  for (int kt = 0; kt < g.K; kt += 32){
#pragma unroll
    for (int p = 0; p < NP; ++p){
#pragma unroll
      for (int r0 = 0; r0 < 2; ++r0){
        long row = r0*64 + srow;
        async16(Ap[p] + (m0 + row)*g.lda + kt + schunk*8, &sm[p*4096      + r0*2048 + wave*512]);
        async16(Bp[p] + (n0 + row)*g.ldb + kt + schunk*8, &sm[(NP+p)*4096 + r0*2048 + wave*512]);
      }
    }
    __syncthreads();
    f16x8 af[NP][4], bf[NP][4];
#pragma unroll
    for (int i = 0; i < 4; ++i){
      int row = wm + i*16 + r;
      int slot = quad ^ ((row >> 1) & 3);
#pragma unroll
      for (int p = 0; p < NP; ++p)
        af[p][i] = ld8h(&sm[p*4096 + row*32 + slot*8]);
    }
#pragma unroll
    for (int j = 0; j < 4; ++j){
      int row = wn + j*16 + r;
      int slot = quad ^ ((row >> 1) & 3);
#pragma unroll
      for (int p = 0; p < NP; ++p)
        bf[p][j] = ld8h(&sm[(NP+p)*4096 + row*32 + slot*8]);
    }
#pragma unroll
    for (int i = 0; i < 4; ++i)
#pragma unroll
      for (int j = 0; j < 4; ++j){
        acc[i][j] = __builtin_amdgcn_mfma_f32_16x16x32_f16(af[0][i], bf[0][j], acc[i][j], 0, 0, 0);
        if (NP == 2){
          accr[i][j] = __builtin_amdgcn_mfma_f32_16x16x32_f16(af[0][i], bf[1][j], accr[i][j], 0, 0, 0);
          accr[i][j] = __builtin_amdgcn_mfma_f32_16x16x32_f16(af[1][i], bf[0][j], accr[i][j], 0, 0, 0);
        }
      }
    __syncthreads();
  }
  // epilogue: C/D layout col=lane&15, row=quad*4+reg
#pragma unroll
  for (int i = 0; i < 4; ++i){
#pragma unroll
    for (int rr = 0; rr < 4; ++rr){
      long row = m0 + wm + i*16 + quad*4 + rr;
#pragma unroll
      for (int j = 0; j < 4; ++j){
        long col = n0 + wn + j*16 + r;
        float v = acc[i][j][rr];
        if (NP == 2) v += accr[i][j][rr] * RINV;
        switch (g.mode){
          case 2: {               // scores (scaled, fp32)
            g.outF[((long)z*KS + row)*KS + col] = v * g.scale;
            break;
          }
          case 4: {               // out-proj: +bias, fp32
            v += g.bias[col];
            g.outF[row*KD + col] = v;
            break;
          }
          case 5: {               // FFN1: +b1, gelu(tanh approx), f16
            v += g.bias[(long)z*g.biasStride + col];
            float u = v + 0.044715f*v*v*v;
            v = 0.5f*v*(1.0f + tanhf(0.7978845608028654f*u));
            g.o0[((long)z*KCAP + row)*KDFF + col] = f2h(v);
            break;
          }
          case 6: {               // FFN2: +b2, f16
            v += g.bias[(long)z*g.biasStride + col];
            g.o0[((long)z*KCAP + row)*KD + col] = f2h(v);
            break;
          }
          default: {              // mode 7: fused QKV -> TOKEN layout, 2-plane split
            v += g.bias[(long)z*g.biasStride + col];
            // all three z-slices written (token, feature): coalesced 32B segments
            u16* d0 = (z < 2) ? (g.o0 + (long)z*2*KPLE) : g.o1;
            u16* d1 = d0 + KPLE;
            long idx = row*KD + col;
            unsigned short x, y; split2v(v, x, y);
            d0[idx] = x; d1[idx] = y;
            break;
          }
        }
      }
    }
  }
}

// ---------------- PV GEMM: per bh, O[512,64] = P[512,512] @ Vt[64,512]^T ---------
// Block tile 128x64, 4 waves as 2(M)x2(N of 32); f16 2-plane 3-term.
__launch_bounds__(256)
__global__ void gemm_pv(const u16* __restrict__ Ph, const u16* __restrict__ Pl,
                        const u16* __restrict__ V0, const u16* __restrict__ V1,
                        u16* __restrict__ O0, u16* __restrict__ O1, int chunkBase){
  __shared__ __align__(16) u16 sm[2*4096 + 2*2048];   // A 2x8KB + B 2x4KB = 24KB
  const int tid  = threadIdx.x;
  const int lane = tid & 63;
  const int wave = tid >> 6;
  const int quad = lane >> 4;
  const int r    = lane & 15;
  const int wm = (wave & 1) * 64;
  const int wn = (wave >> 1) * 32;
  const int gx = gridDim.x;
  const int nwg = gx*(int)gridDim.y;
  int lin = (int)blockIdx.x + gx*(int)blockIdx.y;
  lin = xcd_remap(lin, nwg);
  const int z  = lin / gx;
  const long m0 = (long)(lin % gx) * 128;
  const u16* Ap[2] = { Ph + (long)z*KS*KS,  Pl + (long)z*KS*KS };
  const u16* Bp[2] = { V0 + (long)z*KDH*KS, V1 + (long)z*KDH*KS };
  const int srow   = tid >> 2;
  const int schunk = (tid & 3) ^ ((tid >> 3) & 3);
  f32x4 acc[4][2] = {};
  f32x4 accr[4][2] = {};
  for (int kt = 0; kt < KS; kt += 32){
#pragma unroll
    for (int p = 0; p < 2; ++p){
#pragma unroll
      for (int r0 = 0; r0 < 2; ++r0){
        long row = r0*64 + srow;
        async16(Ap[p] + (m0 + row)*KS + kt + schunk*8, &sm[p*4096 + r0*2048 + wave*512]);
      }
      async16(Bp[p] + srow*KS + kt + schunk*8, &sm[8192 + p*2048 + wave*512]);
    }
    __syncthreads();
    f16x8 af[2][4], bf[2][2];
#pragma unroll
    for (int i = 0; i < 4; ++i){
      int row = wm + i*16 + r;
      int slot = quad ^ ((row >> 1) & 3);
#pragma unroll
      for (int p = 0; p < 2; ++p)
        af[p][i] = ld8h(&sm[p*4096 + row*32 + slot*8]);
    }
#pragma unroll
    for (int j = 0; j < 2; ++j){
      int row = wn + j*16 + r;
      int slot = quad ^ ((row >> 1) & 3);
#pragma unroll
      for (int p = 0; p < 2; ++p)
        bf[p][j] = ld8h(&sm[8192 + p*2048 + row*32 + slot*8]);
    }
#pragma unroll
    for (int i = 0; i < 4; ++i)
#pragma unroll
      for (int j = 0; j < 2; ++j){
        acc[i][j]  = __builtin_amdgcn_mfma_f32_16x16x32_f16(af[0][i], bf[0][j], acc[i][j], 0, 0, 0);
        accr[i][j] = __builtin_amdgcn_mfma_f32_16x16x32_f16(af[0][i], bf[1][j], accr[i][j], 0, 0, 0);
        accr[i][j] = __builtin_amdgcn_mfma_f32_16x16x32_f16(af[1][i], bf[0][j], accr[i][j], 0, 0, 0);
      }
    __syncthreads();
  }
  int bh = chunkBase + z;
  long b = bh >> 4, h = bh & 15;
#pragma unroll
  for (int i = 0; i < 4; ++i){
#pragma unroll
    for (int rr = 0; rr < 4; ++rr){
      long s = m0 + wm + i*16 + quad*4 + rr;
#pragma unroll
      for (int j = 0; j < 2; ++j){
        long col = wn + j*16 + r;
        float v = acc[i][j][rr] + accr[i][j][rr] * RINV;
        long idx = (b*KS + s)*KD + h*KDH + col;
        unsigned short x, y; split2v(v, x, y);
        O0[idx] = x; O1[idx] = y;
      }
    }
  }
}

// ---------------- prep kernels ----------------
__global__ void split2k(const float* __restrict__ x, u16* __restrict__ h,
                        u16* __restrict__ l, long n4){
  long i = (long)blockIdx.x*blockDim.x + threadIdx.x;
  if (i >= n4) return;
  float4 v = ((const float4*)x)[i];
  ushort4 a, b;
  split2v(v.x, a.x, b.x);
  split2v(v.y, a.y, b.y);
  split2v(v.z, a.z, b.z);
  split2v(v.w, a.w, b.w);
  ((ushort4*)h)[i] = a; ((ushort4*)l)[i] = b;
}

// batched transpose: in (z,R,C) f32 -> out (z,C,R) f16
__global__ void trans_b(const float* __restrict__ in, u16* __restrict__ outp, int R, int Cc){
  __shared__ float tile[32][33];
  long z = blockIdx.z;
  const float* ip = in + z*(long)R*Cc;
  u16* op = outp + z*(long)R*Cc;
  int c0 = blockIdx.x*32, r0 = blockIdx.y*32;
  int tx = threadIdx.x, ty = threadIdx.y;
  for (int rr = ty; rr < 32; rr += 8)
    tile[rr][tx] = ip[(long)(r0+rr)*Cc + c0 + tx];
  __syncthreads();
  for (int cc = ty; cc < 32; cc += 8)
    op[(long)(c0+cc)*R + r0 + tx] = f2h(tile[tx][cc]);
}

// V token-plane (token, 1024) u16 -> head-transposed (bh, dh, S) u16, both planes.
// Coalesced 64B reads and writes via 32x32 LDS tile; bitwise passthrough.
__global__ void vtrans(const u16* __restrict__ in0, const u16* __restrict__ in1,
                       u16* __restrict__ out0, u16* __restrict__ out1){
  __shared__ u16 tile[2][32][33];
  int sT = blockIdx.x;       // 0..15  (s tile within b)
  int dT = blockIdx.y;       // 0..31  (global feature tile)
  int b  = blockIdx.z;       // 0..7
  int tx = threadIdx.x;      // 0..31
  int ty = threadIdx.y;      // 0..7
  long srow = (long)b*KS + sT*32;
  int d0 = dT*32;
  for (int rr = ty; rr < 32; rr += 8){
    tile[0][rr][tx] = in0[(srow+rr)*KD + d0 + tx];
    tile[1][rr][tx] = in1[(srow+rr)*KD + d0 + tx];
  }
  __syncthreads();
  int h = d0 >> 6;           // constant per block (d0 multiple of 32)
  int dbase = d0 & 63;
  long obase = ((long)(b*KH + h)*KDH)*KS + sT*32 + tx;
  for (int cc = ty; cc < 32; cc += 8){
    long o = obase + (long)(dbase+cc)*KS;
    out0[o] = tile[0][tx][cc];
    out1[o] = tile[1][tx][cc];
  }
}

// ---------------- softmax over 512-wide rows -> 2-plane f16 P ----------------
__launch_bounds__(64)
__global__ void softmax2(const float* __restrict__ scores, u16* __restrict__ ph,
                         u16* __restrict__ pl){
  long row = blockIdx.x;
  const float* rp = scores + row * KS;
  int lane = threadIdx.x;
  float4 a = ((const float4*)rp)[lane*2];
  float4 b = ((const float4*)rp)[lane*2 + 1];
  float vv[8] = {a.x,a.y,a.z,a.w,b.x,b.y,b.z,b.w};
  float m = vv[0];
#pragma unroll
  for (int t = 1; t < 8; ++t) m = fmaxf(m, vv[t]);
  for (int off = 32; off; off >>= 1) m = fmaxf(m, __shfl_xor(m, off));
  float s = 0.f;
#pragma unroll
  for (int t = 0; t < 8; ++t){ vv[t] = expf(vv[t] - m); s += vv[t]; }
  for (int off = 32; off; off >>= 1) s += __shfl_xor(s, off);
  float inv = 1.0f / s;
  unsigned short hh[8], ll[8];
#pragma unroll
  for (int t = 0; t < 8; ++t) split2v(vv[t] * inv, hh[t], ll[t]);
  ushort4* dh = (ushort4*)(ph + row*KS + lane*8);
  dh[0] = make_ushort4(hh[0],hh[1],hh[2],hh[3]);
  dh[1] = make_ushort4(hh[4],hh[5],hh[6],hh[7]);
  ushort4* dl = (ushort4*)(pl + row*KS + lane*8);
  dl[0] = make_ushort4(ll[0],ll[1],ll[2],ll[3]);
  dl[1] = make_ushort4(ll[4],ll[5],ll[6],ll[7]);
}

// ---------------- LN1 + router (fp32 exact; no contended atomics) ----------------
__launch_bounds__(256)
__global__ void ln1_router(const float* __restrict__ q, const float* __restrict__ attn,
    const float* __restrict__ lnw, const float* __restrict__ lnb, const float* __restrict__ rw,
    float* __restrict__ x1, u16* __restrict__ x1b,
    int* __restrict__ idx0, int* __restrict__ idx1, float* __restrict__ gate0, float* __restrict__ gate1,
    float* __restrict__ ptok, float* __restrict__ lset){
  const int t = blockIdx.x, tid = threadIdx.x;
  const int lane = tid & 63, wid = tid >> 6;
  float4 xv = ((const float4*)(q    + (long)t*KD))[tid];
  float4 av = ((const float4*)(attn + (long)t*KD))[tid];
  xv.x += av.x; xv.y += av.y; xv.z += av.z; xv.w += av.w;
  float s  = xv.x + xv.y + xv.z + xv.w;
  float ss = xv.x*xv.x + xv.y*xv.y + xv.z*xv.z + xv.w*xv.w;
  for (int off = 32; off; off >>= 1){ s += __shfl_xor(s, off); ss += __shfl_xor(ss, off); }
  __shared__ float rs[4], rss[4];
  if (lane == 0){ rs[wid] = s; rss[wid] = ss; }
  __syncthreads();
  float S1 = rs[0]+rs[1]+rs[2]+rs[3];
  float S2 = rss[0]+rss[1]+rss[2]+rss[3];
  float mean = S1 * (1.0f/KD);
  float var  = S2 * (1.0f/KD) - mean*mean;
  float rstd = rsqrtf(var + 1e-5f);
  float4 w4 = ((const float4*)lnw)[tid];
  float4 b4 = ((const float4*)lnb)[tid];
  float y0 = (xv.x - mean)*rstd*w4.x + b4.x;
  float y1 = (xv.y - mean)*rstd*w4.y + b4.y;
  float y2 = (xv.z - mean)*rstd*w4.z + b4.z;
  float y3 = (xv.w - mean)*rstd*w4.w + b4.w;
  float4 yo; yo.x=y0; yo.y=y1; yo.z=y2; yo.w=y3;
  ((float4*)(x1 + (long)t*KD))[tid] = yo;
  ushort4 yb; yb.x=f2h(y0); yb.y=f2h(y1); yb.z=f2h(y2); yb.w=f2h(y3);
  ((ushort4*)(x1b + (long)t*KD))[tid] = yb;
  int d0 = tid*4;
  float rloc[4][8];
#pragma unroll
  for (int c = 0; c < 4; ++c){
    const float4* rp = (const float4*)(rw + (long)(d0 + c)*KE);
    float4 u = rp[0], v2 = rp[1];
    rloc[c][0]=u.x; rloc[c][1]=u.y; rloc[c][2]=u.z; rloc[c][3]=u.w;
    rloc[c][4]=v2.x; rloc[c][5]=v2.y; rloc[c][6]=v2.z; rloc[c][7]=v2.w;
  }
  float yv[4] = {y0,y1,y2,y3};
  float pr[8];
#pragma unroll
  for (int e = 0; e < 8; ++e)
    pr[e] = yv[0]*rloc[0][e] + yv[1]*rloc[1][e] + yv[2]*rloc[2][e] + yv[3]*rloc[3][e];
#pragma unroll
  for (int e = 0; e < 8; ++e)
    for (int off = 32; off; off >>= 1) pr[e] += __shfl_xor(pr[e], off);
  __shared__ float wl[4][8];
  if (lane == 0)
#pragma unroll
    for (int e = 0; e < 8; ++e) wl[wid][e] = pr[e];
  __syncthreads();
  if (tid == 0){
    float lg[8];
#pragma unroll
    for (int e = 0; e < 8; ++e) lg[e] = wl[0][e]+wl[1][e]+wl[2][e]+wl[3][e];
    float mx = lg[0];
    for (int e = 1; e < 8; ++e) mx = fmaxf(mx, lg[e]);
    float pe[8], se = 0.f;
    for (int e = 0; e < 8; ++e){ pe[e] = expf(lg[e]-mx); se += pe[e]; }
    float inv = 1.0f/se;
    for (int e = 0; e < 8; ++e) pe[e] *= inv;
    int e0 = 0;
    for (int e = 1; e < 8; ++e) if (pe[e] > pe[e0]) e0 = e;   // first-index tie break (jax)
    int e1 = (e0 == 0) ? 1 : 0;
    for (int e = 0; e < 8; ++e) if (e != e0 && pe[e] > pe[e1]) e1 = e;
    idx0[t] = e0; idx1[t] = e1;
    gate0[t] = pe[e0]; gate1[t] = pe[e1];
    for (int e = 0; e < 8; ++e) ptok[(long)t*8 + e] = pe[e];
    lset[t] = mx + logf(se);
  }
}

// ---------------- routing scans ----------------
__launch_bounds__(64)
__global__ void scan1(const int* __restrict__ idx0, const int* __restrict__ idx1,
                      int* __restrict__ rnk0, int* __restrict__ rnk1,
                      int* __restrict__ h0, int* __restrict__ h1){
  int lane = threadIdx.x;
  int t = blockIdx.x*64 + lane;
  int i0 = idx0[t], i1 = idx1[t];
  unsigned long long below = (1ull << lane) - 1ull;
  unsigned long long b0[8], b1[8];
#pragma unroll
  for (int e = 0; e < 8; ++e){
    b0[e] = __ballot(i0 == e);
    b1[e] = __ballot(i1 == e);
  }
  rnk0[t] = __popcll(b0[i0] & below);
  rnk1[t] = __popcll(b1[i1] & below);
  if (lane < 8){
    h0[blockIdx.x*8 + lane] = __popcll(b0[lane]);
    h1[blockIdx.x*8 + lane] = __popcll(b1[lane]);
  }
}

__launch_bounds__(64)
__global__ void scan2(const int* __restrict__ h0, const int* __restrict__ h1,
                      int* __restrict__ bs0, int* __restrict__ bs1, int* __restrict__ cnt0){
  int lane = threadIdx.x;  // lane = chunk id (64 chunks)
  for (int e = 0; e < 8; ++e){
    int v = h0[lane*8 + e];
    int x = v;
    for (int off = 1; off < 64; off <<= 1){
      int y = __shfl_up(x, off);
      if (lane >= off) x += y;
    }
    bs0[lane*8 + e] = x - v;
    int tot = __shfl(x, 63);
    if (lane == 0) cnt0[e] = tot;
    int w = h1[lane*8 + e];
    int xx = w;
    for (int off = 1; off < 64; off <<= 1){
      int y = __shfl_up(xx, off);
      if (lane >= off) xx += y;
    }
    bs1[lane*8 + e] = tot + xx - w;
  }
}

__global__ void scan3(const int* __restrict__ idx0, const int* __restrict__ idx1,
                      const int* __restrict__ rnk0, const int* __restrict__ rnk1,
                      const int* __restrict__ bs0, const int* __restrict__ bs1,
                      int* __restrict__ dst0, int* __restrict__ dst1, int* __restrict__ slot){
  int t = blockIdx.x*blockDim.x + threadIdx.x;
  if (t >= KN) return;
  int c = t >> 6;
  int e0 = idx0[t], e1 = idx1[t];
  int p0 = bs0[c*8 + e0] + rnk0[t];
  int p1 = bs1[c*8 + e1] + rnk1[t];
  int d0 = (p0 < KCAP) ? (e0*KCAP + p0) : -1;
  int d1 = (p1 < KCAP) ? (e1*KCAP + p1) : -1;
  dst0[t] = d0; dst1[t] = d1;
  if (d0 >= 0) slot[d0] = t;
  if (d1 >= 0) slot[d1] = t;
}

// ---------------- gather xin ----------------
__launch_bounds__(64)
__global__ void gather_xin(const int* __restrict__ slot_token, const u16* __restrict__ x1b,
                           u16* __restrict__ xin){
  long slot = blockIdx.x;
  int t = slot_token[slot];
  uint4* dst = (uint4*)(xin + slot*KD);
  int lane = threadIdx.x;
  if (t >= 0){
    const uint4* src = (const uint4*)(x1b + (long)t*KD);
    dst[lane*2]   = src[lane*2];
    dst[lane*2+1] = src[lane*2+1];
  } else {
    uint4 zz; zz.x = zz.y = zz.z = zz.w = 0;
    dst[lane*2] = zz; dst[lane*2+1] = zz;
  }
}

// ---------------- combine + LN2 -> output ----------------
__launch_bounds__(256)
__global__ void combine_ln2(const float* __restrict__ x1, const u16* __restrict__ oute,
    const int* __restrict__ dest0, const int* __restrict__ dest1,
    const float* __restrict__ gate0, const float* __restrict__ gate1,
    const float* __restrict__ lnw, const float* __restrict__ lnb, float* __restrict__ out){
  const int t = blockIdx.x, tid = threadIdx.x;
  const int lane = tid & 63, wid = tid >> 6;
  float4 xv = ((const float4*)(x1 + (long)t*KD))[tid];
  int d0 = dest0[t], d1 = dest1[t];
  float g0 = gate0[t], g1 = gate1[t];
  if (d0 >= 0){
    ushort4 o = ((const ushort4*)(oute + (long)d0*KD))[tid];
    xv.x += g0*h2f(o.x); xv.y += g0*h2f(o.y); xv.z += g0*h2f(o.z); xv.w += g0*h2f(o.w);
  }
  if (d1 >= 0){
    ushort4 o = ((const ushort4*)(oute + (long)d1*KD))[tid];
    xv.x += g1*h2f(o.x); xv.y += g1*h2f(o.y); xv.z += g1*h2f(o.z); xv.w += g1*h2f(o.w);
  }
  float s  = xv.x + xv.y + xv.z + xv.w;
  float ss = xv.x*xv.x + xv.y*xv.y + xv.z*xv.z + xv.w*xv.w;
  for (int off = 32; off; off >>= 1){ s += __shfl_xor(s, off); ss += __shfl_xor(ss, off); }
  __shared__ float rs[4], rss[4];
  if (lane == 0){ rs[wid] = s; rss[wid] = ss; }
  __syncthreads();
  float S1 = rs[0]+rs[1]+rs[2]+rs[3];
  float S2 = rss[0]+rss[1]+rss[2]+rss[3];
  float mean = S1 * (1.0f/KD);
  float var  = S2 * (1.0f/KD) - mean*mean;
  float rstd = rsqrtf(var + 1e-5f);
  float4 w4 = ((const float4*)lnw)[tid];
  float4 b4 = ((const float4*)lnb)[tid];
  float4 yo;
  yo.x = (xv.x - mean)*rstd*w4.x + b4.x;
  yo.y = (xv.y - mean)*rstd*w4.y + b4.y;
  yo.z = (xv.z - mean)*rstd*w4.z + b4.z;
  yo.w = (xv.w - mean)*rstd*w4.w + b4.w;
  ((float4*)(out + (long)t*KD))[tid] = yo;
}

// ---------------- aux: tree-reduce per-token probs + lse^2 ----------------
__launch_bounds__(1024)
__global__ void aux_k(const int* __restrict__ cnt0, const float* __restrict__ ptok,
                      const float* __restrict__ lset, float* __restrict__ out){
  int t = threadIdx.x;
  float ps[8] = {0,0,0,0,0,0,0,0};
  float l2 = 0.f;
  for (int i = t; i < KN; i += 1024){
    const float4* p = (const float4*)(ptok + (long)i*8);
    float4 a = p[0], b = p[1];
    ps[0]+=a.x; ps[1]+=a.y; ps[2]+=a.z; ps[3]+=a.w;
    ps[4]+=b.x; ps[5]+=b.y; ps[6]+=b.z; ps[7]+=b.w;
    float l = lset[i]; l2 = fmaf(l, l, l2);
  }
#pragma unroll
  for (int off = 32; off; off >>= 1){
#pragma unroll
    for (int e = 0; e < 8; ++e) ps[e] += __shfl_xor(ps[e], off);
    l2 += __shfl_xor(l2, off);
  }
  __shared__ float sp[16][9];
  int lane = t & 63, wid = t >> 6;
  if (lane == 0){
#pragma unroll
    for (int e = 0; e < 8; ++e) sp[wid][e] = ps[e];
    sp[wid][8] = l2;
  }
  __syncthreads();
  if (t == 0){
    float fin[9];
#pragma unroll
    for (int j = 0; j < 9; ++j){
      float s = 0.f;
      for (int w2 = 0; w2 < 16; ++w2) s += sp[w2][j];
      fin[j] = s;
    }
    float bal = 0.f;
    for (int e = 0; e < 8; ++e)
      bal += ((float)cnt0[e] * (1.0f/KN)) * (fin[e] * (1.0f/KN));
    bal *= (float)KE;
    float zl = fin[8] * (1.0f/KN);
    out[(long)KN*KD] = 0.01f*bal + 0.001f*zl;
  }
}

// ---------------- host ----------------
extern "C" void kernel_launch(void* const* d_in, const int* in_sizes, int n_in,
                              void* d_out, int out_size, void* d_ws, size_t ws_size,
                              hipStream_t stream){
  const float* q    = (const float*)d_in[0];
  const float* k    = (const float*)d_in[1];
  const float* v    = (const float*)d_in[2];
  const float* inw  = (const float*)d_in[3];
  const float* inb  = (const float*)d_in[4];
  const float* outw = (const float*)d_in[5];
  const float* outb = (const float*)d_in[6];
  const float* ln1w = (const float*)d_in[7];
  const float* ln1b = (const float*)d_in[8];
  const float* ln2w = (const float*)d_in[9];
  const float* ln2b = (const float*)d_in[10];
  const float* rw   = (const float*)d_in[11];
  const float* w1   = (const float*)d_in[12];
  const float* b1   = (const float*)d_in[13];
  const float* w2   = (const float*)d_in[14];
  const float* b2   = (const float*)d_in[15];
  float* out = (float*)d_out;
  char* ws = (char*)d_ws;

  constexpr size_t PLB  = (size_t)KN*KD*2;            // 8,388,608 plane bytes
  constexpr long   PLE  = (long)KN*KD;                // plane elements
  constexpr size_t oW1T = 0;                          // 64 MB f16
  constexpr size_t oW2T = oW1T + 67108864;            // 64 MB f16
  constexpr size_t oWQ0 = oW2T + 67108864;            // 6 MB
  constexpr size_t oWQ1 = oWQ0 + 6291456;
  constexpr size_t oWO0 = oWQ1 + 6291456;             // 2 MB
  constexpr size_t oWO1 = oWO0 + 2097152;
  constexpr size_t oX1  = oWO1 + 2097152;             // 16 MB
  constexpr size_t oX1B = oX1  + 16777216;            // 8 MB
  constexpr size_t oMISC= oX1B + 8388608;             // 1 MB
  constexpr size_t oU1  = oMISC + 1048576;            // 84 MB: q/k/v splits -> Vtok -> ATTN+O planes -> HBUF
  constexpr size_t oU2  = oU1 + 83886080;             // 48 MB: qt/kt/vt -> xin + out_e
  constexpr size_t oU3  = oU2 + 50331648;             // 64 MB: SCF + P planes
  constexpr size_t oEND = oU3 + 67108864;             // ~361 MB
  if (ws_size < oEND) return;

  u16* W1T = (u16*)(ws + oW1T);
  u16* W2T = (u16*)(ws + oW2T);
  u16* WQ0 = (u16*)(ws + oWQ0); u16* WQ1 = (u16*)(ws + oWQ1);
  u16* WO0 = (u16*)(ws + oWO0); u16* WO1 = (u16*)(ws + oWO1);
  float* X1 = (float*)(ws + oX1);
  u16* X1B  = (u16*)(ws + oX1B);

  int*   IDX0 = (int*)(ws + oMISC);
  int*   IDX1 = (int*)(ws + oMISC + 16384);
  int*   RNK0 = (int*)(ws + oMISC + 32768);
  int*   RNK1 = (int*)(ws + oMISC + 49152);
  int*   DST0 = (int*)(ws + oMISC + 65536);
  int*   DST1 = (int*)(ws + oMISC + 81920);
  float* G0   = (float*)(ws + oMISC + 98304);
  float* G1   = (float*)(ws + oMISC + 114688);
  int*   H0   = (int*)(ws + oMISC + 131072);
  int*   H1   = (int*)(ws + oMISC + 133120);
  int*   BS0  = (int*)(ws + oMISC + 135168);
  int*   BS1  = (int*)(ws + oMISC + 137216);
  int*   CNT0 = (int*)(ws + oMISC + 139264);
  int*   SLOT = (int*)(ws + oMISC + 139776);
  float* PTOK = (float*)(ws + oMISC + 262144);
  float* LSET = (float*)(ws + oMISC + 393216);

  u16* Qs0 = (u16*)(ws + oU1);           u16* Qs1 = (u16*)(ws + oU1 + PLB);
  u16* Ks0 = (u16*)(ws + oU1 + 2*PLB);   u16* Ks1 = (u16*)(ws + oU1 + 3*PLB);
  u16* Vs0 = (u16*)(ws + oU1 + 4*PLB);   u16* Vs1 = (u16*)(ws + oU1 + 5*PLB);
  u16* VTOK0 = (u16*)(ws + oU1 + 6*PLB); u16* VTOK1 = (u16*)(ws + oU1 + 7*PLB);  // V token planes
  float* ATTN = (float*)(ws + oU1);                          // 16 MB, after splits die
  u16* O0 = (u16*)(ws + oU1 + 16777216);
  u16* O1 = (u16*)(ws + oU1 + 16777216 + PLB);
  u16* HBUF = (u16*)(ws + oU1);                              // 80 MB, after ATTN/O/VTOK die

  u16* QT0 = (u16*)(ws + oU2);           u16* QT1 = (u16*)(ws + oU2 + PLB);      // Q token planes
  u16* KT0 = (u16*)(ws + oU2 + 2*PLB);   u16* KT1 = (u16*)(ws + oU2 + 3*PLB);    // K token planes
  u16* VT0 = (u16*)(ws + oU2 + 4*PLB);   u16* VT1 = (u16*)(ws + oU2 + 5*PLB);    // V (bh,dh,S) planes
  u16* XIN  = (u16*)(ws + oU2);                              // after attention
  u16* OUTE = (u16*)(ws + oU2 + 20971520);

  float* SCF = (float*)(ws + oU3);                           // 33.5 MB fp32
  u16* PH  = (u16*)(ws + oU3 + 33554432);
  u16* PL  = (u16*)(ws + oU3 + 50331648);

  hipMemsetAsync(ws + oMISC + 139776, 0xFF, (size_t)KE*KCAP*4, stream);

  // 2-plane f16 splits (residual plane scaled x4096)
  split2k<<<4096, 256, 0, stream>>>(q, Qs0, Qs1, (long)KN*KD/4);
  split2k<<<4096, 256, 0, stream>>>(k, Ks0, Ks1, (long)KN*KD/4);
  split2k<<<4096, 256, 0, stream>>>(v, Vs0, Vs1, (long)KN*KD/4);
  split2k<<<3072, 256, 0, stream>>>(inw, WQ0, WQ1, 786432);
  split2k<<<1024, 256, 0, stream>>>(outw, WO0, WO1, 262144);

  // FFN weight transposes to (N,K) f16 for NT GEMM
  trans_b<<<dim3(KDFF/32, KD/32, KE), dim3(32,8), 0, stream>>>(w1, W1T, KD, KDFF);
  trans_b<<<dim3(KD/32, KDFF/32, KE), dim3(32,8), 0, stream>>>(w2, W2T, KDFF, KD);

  // fused QKV projections (z=0:Q, 1:K, 2:V), f16 2-plane 3-term -> token layout
  {
    GArgs ga{};
    ga.A0=Qs0; ga.A1=Qs1; ga.lda=KD; ga.sA=2*PLE;
    ga.B0=WQ0; ga.B1=WQ1; ga.ldb=KD; ga.sB=1048576;
    ga.bias=inb; ga.biasStride=KD;
    ga.o0=QT0; ga.o1=VTOK0; ga.outF=nullptr;
    ga.K=KD; ga.mode=7; ga.scale=1.f;
    gemm128<2><<<dim3(8, 32, 3), 256, 0, stream>>>(ga);
  }

  // V: token layout -> (bh, dh, S) for the PV GEMM (u16 passthrough, both planes)
  vtrans<<<dim3(KS/32, KD/32, KB), dim3(32,8), 0, stream>>>(VTOK0, VTOK1, VT0, VT1);

  // attention, chunked over bh (4 chunks of 32)
  for (int c = 0; c < KNCH; ++c){
    long hoff = (long)c * KCHB * KS * KDH;
    GArgs gs{};
    gs.A0=QT0; gs.A1=QT1; gs.lda=KD; gs.sA=0;
    gs.B0=KT0; gs.B1=KT1; gs.ldb=KD; gs.sB=0;
    gs.hbase = c*KCHB;
    gs.bias=nullptr; gs.biasStride=0; gs.outF=SCF; gs.o0=nullptr;
    gs.K=KDH; gs.mode=2; gs.scale=0.125f;
    gemm128<2><<<dim3(4, 4, KCHB), 256, 0, stream>>>(gs);

    softmax2<<<KCHB*KS, 64, 0, stream>>>(SCF, PH, PL);

    gemm_pv<<<dim3(4, KCHB), 256, 0, stream>>>(PH, PL, VT0+hoff, VT1+hoff,
                                               O0, O1, c*KCHB);
  }

  // out-projection -> ATTN fp32
  {
    GArgs go{};
    go.A0=O0; go.A1=O1; go.lda=KD; go.sA=0;
    go.B0=WO0; go.B1=WO1; go.ldb=KD; go.sB=0;
    go.bias=outb; go.biasStride=0; go.outF=ATTN; go.o0=nullptr;
    go.K=KD; go.mode=4; go.scale=1.f;
    gemm128<2><<<dim3(8, 32, 1), 256, 0, stream>>>(go);
  }

  // LN1 + router
  ln1_router<<<KN, 256, 0, stream>>>(q, ATTN, ln1w, ln1b, rw, X1, X1B,
                                     IDX0, IDX1, G0, G1, PTOK, LSET);
  // capacity-ordered routing
  scan1<<<64, 64, 0, stream>>>(IDX0, IDX1, RNK0, RNK1, H0, H1);
  scan2<<<1, 64, 0, stream>>>(H0, H1, BS0, BS1, CNT0);
  scan3<<<16, 256, 0, stream>>>(IDX0, IDX1, RNK0, RNK1, BS0, BS1, DST0, DST1, SLOT);
  aux_k<<<1, 1024, 0, stream>>>(CNT0, PTOK, LSET, out);
  gather_xin<<<KE*KCAP, 64, 0, stream>>>(SLOT, X1B, XIN);

  // expert FFN (plain f16, 1-plane)
  {
    GArgs f1{};
    f1.A0=XIN; f1.A1=nullptr; f1.lda=KD; f1.sA=(long)KCAP*KD;
    f1.B0=W1T; f1.B1=nullptr; f1.ldb=KD; f1.sB=(long)KDFF*KD;
    f1.bias=b1; f1.biasStride=KDFF; f1.outF=nullptr; f1.o0=HBUF;
    f1.K=KD; f1.mode=5; f1.scale=1.f;
    gemm128<1><<<dim3(KDFF/128, KCAP/128, KE), 256, 0, stream>>>(f1);

    GArgs f2{};
    f2.A0=HBUF; f2.A1=nullptr; f2.lda=KDFF; f2.sA=(long)KCAP*KDFF;
    f2.B0=W2T; f2.B1=nullptr; f2.ldb=KDFF; f2.sB=(long)KD*KDFF;
    f2.bias=b2; f2.biasStride=KD; f2.outF=nullptr; f2.o0=OUTE;
    f2.K=KDFF; f2.mode=6; f2.scale=1.f;
    gemm128<1><<<dim3(KD/128, KCAP/128, KE), 256, 0, stream>>>(f2);
  }

  // combine + LN2 -> output
  combine_ln2<<<KN, 256, 0, stream>>>(X1, OUTE, DST0, DST1, G0, G1, ln2w, ln2b, out);
}

// Round 3
// 1213.734 us; speedup vs baseline: 1.1134x; 1.0538x over previous
//
#include <hip/hip_runtime.h>
#include <cstdint>
#include <cstddef>

// ---------------- constants ----------------
#define KB   8
#define KS   512
#define KD   1024
#define KH   16
#define KDH  64
#define KE   8
#define KDFF 4096
#define KN   4096      // B*S tokens
#define KCAP 1280      // ceil(2*4096/8*1.25)
#define KCHB 32        // attention bh per chunk
#define KNCH 4         // 128 / KCHB
#define KPLE ((long)KN*KD)   // plane elements

typedef unsigned short u16;
typedef _Float16 f16;
typedef f16   f16x8 __attribute__((ext_vector_type(8)));
typedef float f32x4 __attribute__((ext_vector_type(4)));

#define RSCALE 4096.0f
#define RINV   2.44140625e-4f   // 1/4096

__device__ __forceinline__ u16 f2h(float f){
  f16 h = (f16)f;
  return __builtin_bit_cast(u16, h);
}
__device__ __forceinline__ float h2f(u16 u){
  f16 h = __builtin_bit_cast(f16, u);
  return (float)h;
}
// 2-plane f16 split; residual plane pre-scaled x4096 so it stays in f16
// normal range (guards against possible MFMA denorm-input flush).
__device__ __forceinline__ void split2v(float f, u16 &a, u16 &b){
  f16 h0 = (f16)f;
  float r = (f - (float)h0) * RSCALE;
  a = __builtin_bit_cast(u16, h0);
  b = f2h(r);
}
__device__ __forceinline__ f16x8 ld8h(const u16* p){
  uint4 v = *(const uint4*)p;
  return __builtin_bit_cast(f16x8, v);
}
// async global->LDS, 16B per lane; lds ptr must be wave-uniform (HW adds lane*16)
__device__ __forceinline__ void async16(const u16* g, u16* l){
  __builtin_amdgcn_global_load_lds(
      (const __attribute__((address_space(1))) unsigned int*)(g),
      (__attribute__((address_space(3))) unsigned int*)(l),
      16, 0, 0);
}

// bijective XCD-aware remap (m204): dispatch id -> work id so each XCD
// gets a contiguous chunk of the grid (per-XCD L2 locality).
__device__ __forceinline__ int xcd_remap(int lin, int nwg){
  int qq = nwg >> 3, r8 = nwg & 7;
  int xcd = lin & 7, pos = lin >> 3;
  return (xcd < r8 ? xcd*(qq+1) : r8*(qq+1) + (xcd-r8)*qq) + pos;
}

struct GArgs {
  const u16 *A0, *A1;
  const u16 *B0, *B1;
  long lda, sA, ldb, sB;         // element strides
  const float* bias; long biasStride;
  float* outF;
  u16 *o0;
  u16 *o1;                       // mode 7: V token-plane base
  int K, mode;
  int hbase;                     // mode 2: chunk base bh
  float scale;
};

// ---------------- 128x128 4-wave GEMM, LDS double-buffered 2-phase ----------
// NP=2: A,B are (main, residual*4096) f16 planes; 3-term product ~ fp32 accuracy.
// R3: T3 minimal 2-phase pipeline — STAGE(next buf) issued BEFORE COMPUTE(cur),
// __syncthreads() (vmcnt(0)+lgkmcnt(0)+s_barrier) as the per-K-step drain.
// Prefetch latency is hidden under the MFMA phase; the drain is race-free
// (raw vmcnt-only barrier in R2 had a ds_read/STAGE overwrite race — m152).
template<int NP>
__launch_bounds__(256)
__global__ void gemm128(GArgs g){
  constexpr int BUF = NP*2*4096;              // u16 elements per LDS buffer
  __shared__ __align__(16) u16 sm[2*BUF];
  const int tid  = threadIdx.x;
  const int lane = tid & 63;
  const int wave = tid >> 6;
  const int quad = lane >> 4;
  const int r    = lane & 15;
  const int wm = (wave & 1) * 64;
  const int wn = (wave >> 1) * 64;
  // XCD-aware block remap (all grids here are multiples of 8)
  const int gx = gridDim.x, gy = gridDim.y;
  const int nwg = gx*gy*(int)gridDim.z;
  int lin = (int)blockIdx.x + gx*((int)blockIdx.y + gy*(int)blockIdx.z);
  lin = xcd_remap(lin, nwg);
  const int bx = lin % gx;
  const int byy = (lin / gx) % gy;
  const int z  = lin / (gx*gy);
  const long m0 = (long)byy * 128;
  const long n0 = (long)bx * 128;
  const u16* Ap[NP]; const u16* Bp[NP];
  if (g.mode == 2){
    // token-layout heads: offset = (b)*KS*KD + h*KDH
    int bh = g.hbase + z;
    long off = ((long)(bh >> 4)*KS)*KD + (long)(bh & 15)*KDH;
    Ap[0] = g.A0 + off; Bp[0] = g.B0 + off;
    if (NP == 2){ Ap[1] = g.A1 + off; Bp[1] = g.B1 + off; }
  } else {
    Ap[0] = g.A0 + (long)z*g.sA; Bp[0] = g.B0 + (long)z*g.sB;
    if (NP == 2){ Ap[1] = g.A1 + (long)z*g.sA; Bp[1] = g.B1 + (long)z*g.sB; }
  }
  const int srow   = tid >> 2;
  const int schunk = (tid & 3) ^ ((tid >> 3) & 3);
  f32x4 acc[4][4] = {};
  f32x4 accr[4][4] = {};          // cross-term accumulator (NP==2 only; elided otherwise)

  auto STAGE = [&](int buf, int kt){
#pragma unroll
    for (int p = 0; p < NP; ++p){
#pragma unroll
      for (int r0 = 0; r0 < 2; ++r0){
        long row = r0*64 + srow;
        async16(Ap[p] + (m0 + row)*g.lda + kt + schunk*8, &sm[buf + p*4096      + r0*2048 + wave*512]);
        async16(Bp[p] + (n0 + row)*g.ldb + kt + schunk*8, &sm[buf + (NP+p)*4096 + r0*2048 + wave*512]);
      }
    }
  };
  auto COMPUTE = [&](int buf){
    f16x8 af[NP][4], bf[NP][4];
#pragma unroll
    for (int i = 0; i < 4; ++i){
      int row = wm + i*16 + r;
      int slot = quad ^ ((row >> 1) & 3);
#pragma unroll
      for (int p = 0; p < NP; ++p)
        af[p][i] = ld8h(&sm[buf + p*4096 + row*32 + slot*8]);
    }
#pragma unroll
    for (int j = 0; j < 4; ++j){
      int row = wn + j*16 + r;
      int slot = quad ^ ((row >> 1) & 3);
#pragma unroll
      for (int p = 0; p < NP; ++p)
        bf[p][j] = ld8h(&sm[buf + (NP+p)*4096 + row*32 + slot*8]);
    }
#pragma unroll
    for (int i = 0; i < 4; ++i)
#pragma unroll
      for (int j = 0; j < 4; ++j){
        acc[i][j] = __builtin_amdgcn_mfma_f32_16x16x32_f16(af[0][i], bf[0][j], acc[i][j], 0, 0, 0);
        if (NP == 2){
          accr[i][j] = __builtin_amdgcn_mfma_f32_16x16x32_f16(af[0][i], bf[1][j], accr[i][j], 0, 0, 0);
          accr[i][j] = __builtin_amdgcn_mfma_f32_16x16x32_f16(af[1][i], bf[0][j], accr[i][j], 0, 0, 0);
        }
      }
  };

  const int nk = g.K >> 5;        // always even (K in {64,512,1024,4096})
  STAGE(0, 0);
  __syncthreads();
  for (int it = 0; it < nk - 2; it += 2){
    STAGE(BUF, (it+1) << 5);
    COMPUTE(0);
    __syncthreads();
    STAGE(0, (it+2) << 5);
    COMPUTE(BUF);
    __syncthreads();
  }
  STAGE(BUF, (nk-1) << 5);
  COMPUTE(0);
  __syncthreads();
  COMPUTE(BUF);

  // epilogue: C/D layout col=lane&15, row=quad*4+reg
#pragma unroll
  for (int i = 0; i < 4; ++i){
#pragma unroll
    for (int rr = 0; rr < 4; ++rr){
      long row = m0 + wm + i*16 + quad*4 + rr;
#pragma unroll
      for (int j = 0; j < 4; ++j){
        long col = n0 + wn + j*16 + r;
        float v = acc[i][j][rr];
        if (NP == 2) v += accr[i][j][rr] * RINV;
        switch (g.mode){
          case 2: {               // scores (scaled, fp32)
            g.outF[((long)z*KS + row)*KS + col] = v * g.scale;
            break;
          }
          case 4: {               // out-proj: +bias, fp32
            v += g.bias[col];
            g.outF[row*KD + col] = v;
            break;
          }
          case 5: {               // FFN1: +b1, gelu(tanh approx), f16
            v += g.bias[(long)z*g.biasStride + col];
            float u = v + 0.044715f*v*v*v;
            v = 0.5f*v*(1.0f + tanhf(0.7978845608028654f*u));
            g.o0[((long)z*KCAP + row)*KDFF + col] = f2h(v);
            break;
          }
          case 6: {               // FFN2: +b2, f16
            v += g.bias[(long)z*g.biasStride + col];
            g.o0[((long)z*KCAP + row)*KD + col] = f2h(v);
            break;
          }
          default: {              // mode 7: fused QKV -> TOKEN layout, 2-plane split
            v += g.bias[(long)z*g.biasStride + col];
            // all three z-slices written (token, feature): coalesced 32B segments
            u16* d0 = (z < 2) ? (g.o0 + (long)z*2*KPLE) : g.o1;
            u16* d1 = d0 + KPLE;
            long idx = row*KD + col;
            unsigned short x, y; split2v(v, x, y);
            d0[idx] = x; d1[idx] = y;
            break;
          }
        }
      }
    }
  }
}

// ---------------- PV GEMM: per bh, O[512,64] = P[512,512] @ Vt[64,512]^T ---------
// Block tile 128x64, 4 waves as 2(M)x2(N of 32); f16 2-plane 3-term.
// R3: same race-free 2-phase double-buffer as gemm128.
__launch_bounds__(256)
__global__ void gemm_pv(const u16* __restrict__ Ph, const u16* __restrict__ Pl,
                        const u16* __restrict__ V0, const u16* __restrict__ V1,
                        u16* __restrict__ O0, u16* __restrict__ O1, int chunkBase){
  constexpr int BUF = 2*4096 + 2*2048;                // 12288 u16 = 24 KB
  __shared__ __align__(16) u16 sm[2*BUF];             // 48 KB
  const int tid  = threadIdx.x;
  const int lane = tid & 63;
  const int wave = tid >> 6;
  const int quad = lane >> 4;
  const int r    = lane & 15;
  const int wm = (wave & 1) * 64;
  const int wn = (wave >> 1) * 32;
  const int gx = gridDim.x;
  const int nwg = gx*(int)gridDim.y;
  int lin = (int)blockIdx.x + gx*(int)blockIdx.y;
  lin = xcd_remap(lin, nwg);
  const int z  = lin / gx;
  const long m0 = (long)(lin % gx) * 128;
  const u16* Ap[2] = { Ph + (long)z*KS*KS,  Pl + (long)z*KS*KS };
  const u16* Bp[2] = { V0 + (long)z*KDH*KS, V1 + (long)z*KDH*KS };
  const int srow   = tid >> 2;
  const int schunk = (tid & 3) ^ ((tid >> 3) & 3);
  f32x4 acc[4][2] = {};
  f32x4 accr[4][2] = {};

  auto STAGE = [&](int buf, int kt){
#pragma unroll
    for (int p = 0; p < 2; ++p){
#pragma unroll
      for (int r0 = 0; r0 < 2; ++r0){
        long row = r0*64 + srow;
        async16(Ap[p] + (m0 + row)*KS + kt + schunk*8, &sm[buf + p*4096 + r0*2048 + wave*512]);
      }
      async16(Bp[p] + srow*KS + kt + schunk*8, &sm[buf + 8192 + p*2048 + wave*512]);
    }
  };
  auto COMPUTE = [&](int buf){
    f16x8 af[2][4], bf[2][2];
#pragma unroll
    for (int i = 0; i < 4; ++i){
      int row = wm + i*16 + r;
      int slot = quad ^ ((row >> 1) & 3);
#pragma unroll
      for (int p = 0; p < 2; ++p)
        af[p][i] = ld8h(&sm[buf + p*4096 + row*32 + slot*8]);
    }
#pragma unroll
    for (int j = 0; j < 2; ++j){
      int row = wn + j*16 + r;
      int slot = quad ^ ((row >> 1) & 3);
#pragma unroll
      for (int p = 0; p < 2; ++p)
        bf[p][j] = ld8h(&sm[buf + 8192 + p*2048 + row*32 + slot*8]);
    }
#pragma unroll
    for (int i = 0; i < 4; ++i)
#pragma unroll
      for (int j = 0; j < 2; ++j){
        acc[i][j]  = __builtin_amdgcn_mfma_f32_16x16x32_f16(af[0][i], bf[0][j], acc[i][j], 0, 0, 0);
        accr[i][j] = __builtin_amdgcn_mfma_f32_16x16x32_f16(af[0][i], bf[1][j], accr[i][j], 0, 0, 0);
        accr[i][j] = __builtin_amdgcn_mfma_f32_16x16x32_f16(af[1][i], bf[0][j], accr[i][j], 0, 0, 0);
      }
  };

  const int nk = KS >> 5;   // 16
  STAGE(0, 0);
  __syncthreads();
  for (int it = 0; it < nk - 2; it += 2){
    STAGE(BUF, (it+1) << 5);
    COMPUTE(0);
    __syncthreads();
    STAGE(0, (it+2) << 5);
    COMPUTE(BUF);
    __syncthreads();
  }
  STAGE(BUF, (nk-1) << 5);
  COMPUTE(0);
  __syncthreads();
  COMPUTE(BUF);

  int bh = chunkBase + z;
  long b = bh >> 4, h = bh & 15;
#pragma unroll
  for (int i = 0; i < 4; ++i){
#pragma unroll
    for (int rr = 0; rr < 4; ++rr){
      long s = m0 + wm + i*16 + quad*4 + rr;
#pragma unroll
      for (int j = 0; j < 2; ++j){
        long col = wn + j*16 + r;
        float v = acc[i][j][rr] + accr[i][j][rr] * RINV;
        long idx = (b*KS + s)*KD + h*KDH + col;
        unsigned short x, y; split2v(v, x, y);
        O0[idx] = x; O1[idx] = y;
      }
    }
  }
}

// ---------------- prep kernels ----------------
__global__ void split2k(const float* __restrict__ x, u16* __restrict__ h,
                        u16* __restrict__ l, long n4){
  long i = (long)blockIdx.x*blockDim.x + threadIdx.x;
  if (i >= n4) return;
  float4 v = ((const float4*)x)[i];
  ushort4 a, b;
  split2v(v.x, a.x, b.x);
  split2v(v.y, a.y, b.y);
  split2v(v.z, a.z, b.z);
  split2v(v.w, a.w, b.w);
  ((ushort4*)h)[i] = a; ((ushort4*)l)[i] = b;
}

// batched transpose: in (z,R,C) f32 -> out (z,C,R) f16
__global__ void trans_b(const float* __restrict__ in, u16* __restrict__ outp, int R, int Cc){
  __shared__ float tile[32][33];
  long z = blockIdx.z;
  const float* ip = in + z*(long)R*Cc;
  u16* op = outp + z*(long)R*Cc;
  int c0 = blockIdx.x*32, r0 = blockIdx.y*32;
  int tx = threadIdx.x, ty = threadIdx.y;
  for (int rr = ty; rr < 32; rr += 8)
    tile[rr][tx] = ip[(long)(r0+rr)*Cc + c0 + tx];
  __syncthreads();
  for (int cc = ty; cc < 32; cc += 8)
    op[(long)(c0+cc)*R + r0 + tx] = f2h(tile[tx][cc]);
}

// V token-plane (token, 1024) u16 -> head-transposed (bh, dh, S) u16, both planes.
// Coalesced 64B reads and writes via 32x32 LDS tile; bitwise passthrough.
__global__ void vtrans(const u16* __restrict__ in0, const u16* __restrict__ in1,
                       u16* __restrict__ out0, u16* __restrict__ out1){
  __shared__ u16 tile[2][32][33];
  int sT = blockIdx.x;       // 0..15  (s tile within b)
  int dT = blockIdx.y;       // 0..31  (global feature tile)
  int b  = blockIdx.z;       // 0..7
  int tx = threadIdx.x;      // 0..31
  int ty = threadIdx.y;      // 0..7
  long srow = (long)b*KS + sT*32;
  int d0 = dT*32;
  for (int rr = ty; rr < 32; rr += 8){
    tile[0][rr][tx] = in0[(srow+rr)*KD + d0 + tx];
    tile[1][rr][tx] = in1[(srow+rr)*KD + d0 + tx];
  }
  __syncthreads();
  int h = d0 >> 6;           // constant per block (d0 multiple of 32)
  int dbase = d0 & 63;
  long obase = ((long)(b*KH + h)*KDH)*KS + sT*32 + tx;
  for (int cc = ty; cc < 32; cc += 8){
    long o = obase + (long)(dbase+cc)*KS;
    out0[o] = tile[0][tx][cc];
    out1[o] = tile[1][tx][cc];
  }
}

// ---------------- softmax over 512-wide rows -> 2-plane f16 P ----------------
__launch_bounds__(64)
__global__ void softmax2(const float* __restrict__ scores, u16* __restrict__ ph,
                         u16* __restrict__ pl){
  long row = blockIdx.x;
  const float* rp = scores + row * KS;
  int lane = threadIdx.x;
  float4 a = ((const float4*)rp)[lane*2];
  float4 b = ((const float4*)rp)[lane*2 + 1];
  float vv[8] = {a.x,a.y,a.z,a.w,b.x,b.y,b.z,b.w};
  float m = vv[0];
#pragma unroll
  for (int t = 1; t < 8; ++t) m = fmaxf(m, vv[t]);
  for (int off = 32; off; off >>= 1) m = fmaxf(m, __shfl_xor(m, off));
  float s = 0.f;
#pragma unroll
  for (int t = 0; t < 8; ++t){ vv[t] = expf(vv[t] - m); s += vv[t]; }
  for (int off = 32; off; off >>= 1) s += __shfl_xor(s, off);
  float inv = 1.0f / s;
  unsigned short hh[8], ll[8];
#pragma unroll
  for (int t = 0; t < 8; ++t) split2v(vv[t] * inv, hh[t], ll[t]);
  ushort4* dh = (ushort4*)(ph + row*KS + lane*8);
  dh[0] = make_ushort4(hh[0],hh[1],hh[2],hh[3]);
  dh[1] = make_ushort4(hh[4],hh[5],hh[6],hh[7]);
  ushort4* dl = (ushort4*)(pl + row*KS + lane*8);
  dl[0] = make_ushort4(ll[0],ll[1],ll[2],ll[3]);
  dl[1] = make_ushort4(ll[4],ll[5],ll[6],ll[7]);
}

// ---------------- LN1 + router (fp32 exact; no contended atomics) ----------------
__launch_bounds__(256)
__global__ void ln1_router(const float* __restrict__ q, const float* __restrict__ attn,
    const float* __restrict__ lnw, const float* __restrict__ lnb, const float* __restrict__ rw,
    float* __restrict__ x1, u16* __restrict__ x1b,
    int* __restrict__ idx0, int* __restrict__ idx1, float* __restrict__ gate0, float* __restrict__ gate1,
    float* __restrict__ ptok, float* __restrict__ lset){
  const int t = blockIdx.x, tid = threadIdx.x;
  const int lane = tid & 63, wid = tid >> 6;
  float4 xv = ((const float4*)(q    + (long)t*KD))[tid];
  float4 av = ((const float4*)(attn + (long)t*KD))[tid];
  xv.x += av.x; xv.y += av.y; xv.z += av.z; xv.w += av.w;
  float s  = xv.x + xv.y + xv.z + xv.w;
  float ss = xv.x*xv.x + xv.y*xv.y + xv.z*xv.z + xv.w*xv.w;
  for (int off = 32; off; off >>= 1){ s += __shfl_xor(s, off); ss += __shfl_xor(ss, off); }
  __shared__ float rs[4], rss[4];
  if (lane == 0){ rs[wid] = s; rss[wid] = ss; }
  __syncthreads();
  float S1 = rs[0]+rs[1]+rs[2]+rs[3];
  float S2 = rss[0]+rss[1]+rss[2]+rss[3];
  float mean = S1 * (1.0f/KD);
  float var  = S2 * (1.0f/KD) - mean*mean;
  float rstd = rsqrtf(var + 1e-5f);
  float4 w4 = ((const float4*)lnw)[tid];
  float4 b4 = ((const float4*)lnb)[tid];
  float y0 = (xv.x - mean)*rstd*w4.x + b4.x;
  float y1 = (xv.y - mean)*rstd*w4.y + b4.y;
  float y2 = (xv.z - mean)*rstd*w4.z + b4.z;
  float y3 = (xv.w - mean)*rstd*w4.w + b4.w;
  float4 yo; yo.x=y0; yo.y=y1; yo.z=y2; yo.w=y3;
  ((float4*)(x1 + (long)t*KD))[tid] = yo;
  ushort4 yb; yb.x=f2h(y0); yb.y=f2h(y1); yb.z=f2h(y2); yb.w=f2h(y3);
  ((ushort4*)(x1b + (long)t*KD))[tid] = yb;
  int d0 = tid*4;
  float rloc[4][8];
#pragma unroll
  for (int c = 0; c < 4; ++c){
    const float4* rp = (const float4*)(rw + (long)(d0 + c)*KE);
    float4 u = rp[0], v2 = rp[1];
    rloc[c][0]=u.x; rloc[c][1]=u.y; rloc[c][2]=u.z; rloc[c][3]=u.w;
    rloc[c][4]=v2.x; rloc[c][5]=v2.y; rloc[c][6]=v2.z; rloc[c][7]=v2.w;
  }
  float yv[4] = {y0,y1,y2,y3};
  float pr[8];
#pragma unroll
  for (int e = 0; e < 8; ++e)
    pr[e] = yv[0]*rloc[0][e] + yv[1]*rloc[1][e] + yv[2]*rloc[2][e] + yv[3]*rloc[3][e];
#pragma unroll
  for (int e = 0; e < 8; ++e)
    for (int off = 32; off; off >>= 1) pr[e] += __shfl_xor(pr[e], off);
  __shared__ float wl[4][8];
  if (lane == 0)
#pragma unroll
    for (int e = 0; e < 8; ++e) wl[wid][e] = pr[e];
  __syncthreads();
  if (tid == 0){
    float lg[8];
#pragma unroll
    for (int e = 0; e < 8; ++e) lg[e] = wl[0][e]+wl[1][e]+wl[2][e]+wl[3][e];
    float mx = lg[0];
    for (int e = 1; e < 8; ++e) mx = fmaxf(mx, lg[e]);
    float pe[8], se = 0.f;
    for (int e = 0; e < 8; ++e){ pe[e] = expf(lg[e]-mx); se += pe[e]; }
    float inv = 1.0f/se;
    for (int e = 0; e < 8; ++e) pe[e] *= inv;
    int e0 = 0;
    for (int e = 1; e < 8; ++e) if (pe[e] > pe[e0]) e0 = e;   // first-index tie break (jax)
    int e1 = (e0 == 0) ? 1 : 0;
    for (int e = 0; e < 8; ++e) if (e != e0 && pe[e] > pe[e1]) e1 = e;
    idx0[t] = e0; idx1[t] = e1;
    gate0[t] = pe[e0]; gate1[t] = pe[e1];
    for (int e = 0; e < 8; ++e) ptok[(long)t*8 + e] = pe[e];
    lset[t] = mx + logf(se);
  }
}

// ---------------- routing scans ----------------
__launch_bounds__(64)
__global__ void scan1(const int* __restrict__ idx0, const int* __restrict__ idx1,
                      int* __restrict__ rnk0, int* __restrict__ rnk1,
                      int* __restrict__ h0, int* __restrict__ h1){
  int lane = threadIdx.x;
  int t = blockIdx.x*64 + lane;
  int i0 = idx0[t], i1 = idx1[t];
  unsigned long long below = (1ull << lane) - 1ull;
  unsigned long long b0[8], b1[8];
#pragma unroll
  for (int e = 0; e < 8; ++e){
    b0[e] = __ballot(i0 == e);
    b1[e] = __ballot(i1 == e);
  }
  rnk0[t] = __popcll(b0[i0] & below);
  rnk1[t] = __popcll(b1[i1] & below);
  if (lane < 8){
    h0[blockIdx.x*8 + lane] = __popcll(b0[lane]);
    h1[blockIdx.x*8 + lane] = __popcll(b1[lane]);
  }
}

__launch_bounds__(64)
__global__ void scan2(const int* __restrict__ h0, const int* __restrict__ h1,
                      int* __restrict__ bs0, int* __restrict__ bs1, int* __restrict__ cnt0){
  int lane = threadIdx.x;  // lane = chunk id (64 chunks)
  for (int e = 0; e < 8; ++e){
    int v = h0[lane*8 + e];
    int x = v;
    for (int off = 1; off < 64; off <<= 1){
      int y = __shfl_up(x, off);
      if (lane >= off) x += y;
    }
    bs0[lane*8 + e] = x - v;
    int tot = __shfl(x, 63);
    if (lane == 0) cnt0[e] = tot;
    int w = h1[lane*8 + e];
    int xx = w;
    for (int off = 1; off < 64; off <<= 1){
      int y = __shfl_up(xx, off);
      if (lane >= off) xx += y;
    }
    bs1[lane*8 + e] = tot + xx - w;
  }
}

__global__ void scan3(const int* __restrict__ idx0, const int* __restrict__ idx1,
                      const int* __restrict__ rnk0, const int* __restrict__ rnk1,
                      const int* __restrict__ bs0, const int* __restrict__ bs1,
                      int* __restrict__ dst0, int* __restrict__ dst1, int* __restrict__ slot){
  int t = blockIdx.x*blockDim.x + threadIdx.x;
  if (t >= KN) return;
  int c = t >> 6;
  int e0 = idx0[t], e1 = idx1[t];
  int p0 = bs0[c*8 + e0] + rnk0[t];
  int p1 = bs1[c*8 + e1] + rnk1[t];
  int d0 = (p0 < KCAP) ? (e0*KCAP + p0) : -1;
  int d1 = (p1 < KCAP) ? (e1*KCAP + p1) : -1;
  dst0[t] = d0; dst1[t] = d1;
  if (d0 >= 0) slot[d0] = t;
  if (d1 >= 0) slot[d1] = t;
}

// ---------------- gather xin ----------------
__launch_bounds__(64)
__global__ void gather_xin(const int* __restrict__ slot_token, const u16* __restrict__ x1b,
                           u16* __restrict__ xin){
  long slot = blockIdx.x;
  int t = slot_token[slot];
  uint4* dst = (uint4*)(xin + slot*KD);
  int lane = threadIdx.x;
  if (t >= 0){
    const uint4* src = (const uint4*)(x1b + (long)t*KD);
    dst[lane*2]   = src[lane*2];
    dst[lane*2+1] = src[lane*2+1];
  } else {
    uint4 zz; zz.x = zz.y = zz.z = zz.w = 0;
    dst[lane*2] = zz; dst[lane*2+1] = zz;
  }
}

// ---------------- combine + LN2 -> output ----------------
__launch_bounds__(256)
__global__ void combine_ln2(const float* __restrict__ x1, const u16* __restrict__ oute,
    const int* __restrict__ dest0, const int* __restrict__ dest1,
    const float* __restrict__ gate0, const float* __restrict__ gate1,
    const float* __restrict__ lnw, const float* __restrict__ lnb, float* __restrict__ out){
  const int t = blockIdx.x, tid = threadIdx.x;
  const int lane = tid & 63, wid = tid >> 6;
  float4 xv = ((const float4*)(x1 + (long)t*KD))[tid];
  int d0 = dest0[t], d1 = dest1[t];
  float g0 = gate0[t], g1 = gate1[t];
  if (d0 >= 0){
    ushort4 o = ((const ushort4*)(oute + (long)d0*KD))[tid];
    xv.x += g0*h2f(o.x); xv.y += g0*h2f(o.y); xv.z += g0*h2f(o.z); xv.w += g0*h2f(o.w);
  }
  if (d1 >= 0){
    ushort4 o = ((const ushort4*)(oute + (long)d1*KD))[tid];
    xv.x += g1*h2f(o.x); xv.y += g1*h2f(o.y); xv.z += g1*h2f(o.z); xv.w += g1*h2f(o.w);
  }
  float s  = xv.x + xv.y + xv.z + xv.w;
  float ss = xv.x*xv.x + xv.y*xv.y + xv.z*xv.z + xv.w*xv.w;
  for (int off = 32; off; off >>= 1){ s += __shfl_xor(s, off); ss += __shfl_xor(ss, off); }
  __shared__ float rs[4], rss[4];
  if (lane == 0){ rs[wid] = s; rss[wid] = ss; }
  __syncthreads();
  float S1 = rs[0]+rs[1]+rs[2]+rs[3];
  float S2 = rss[0]+rss[1]+rss[2]+rss[3];
  float mean = S1 * (1.0f/KD);
  float var  = S2 * (1.0f/KD) - mean*mean;
  float rstd = rsqrtf(var + 1e-5f);
  float4 w4 = ((const float4*)lnw)[tid];
  float4 b4 = ((const float4*)lnb)[tid];
  float4 yo;
  yo.x = (xv.x - mean)*rstd*w4.x + b4.x;
  yo.y = (xv.y - mean)*rstd*w4.y + b4.y;
  yo.z = (xv.z - mean)*rstd*w4.z + b4.z;
  yo.w = (xv.w - mean)*rstd*w4.w + b4.w;
  ((float4*)(out + (long)t*KD))[tid] = yo;
}

// ---------------- aux: tree-reduce per-token probs + lse^2 ----------------
__launch_bounds__(1024)
__global__ void aux_k(const int* __restrict__ cnt0, const float* __restrict__ ptok,
                      const float* __restrict__ lset, float* __restrict__ out){
  int t = threadIdx.x;
  float ps[8] = {0,0,0,0,0,0,0,0};
  float l2 = 0.f;
  for (int i = t; i < KN; i += 1024){
    const float4* p = (const float4*)(ptok + (long)i*8);
    float4 a = p[0], b = p[1];
    ps[0]+=a.x; ps[1]+=a.y; ps[2]+=a.z; ps[3]+=a.w;
    ps[4]+=b.x; ps[5]+=b.y; ps[6]+=b.z; ps[7]+=b.w;
    float l = lset[i]; l2 = fmaf(l, l, l2);
  }
#pragma unroll
  for (int off = 32; off; off >>= 1){
#pragma unroll
    for (int e = 0; e < 8; ++e) ps[e] += __shfl_xor(ps[e], off);
    l2 += __shfl_xor(l2, off);
  }
  __shared__ float sp[16][9];
  int lane = t & 63, wid = t >> 6;
  if (lane == 0){
#pragma unroll
    for (int e = 0; e < 8; ++e) sp[wid][e] = ps[e];
    sp[wid][8] = l2;
  }
  __syncthreads();
  if (t == 0){
    float fin[9];
#pragma unroll
    for (int j = 0; j < 9; ++j){
      float s = 0.f;
      for (int w2 = 0; w2 < 16; ++w2) s += sp[w2][j];
      fin[j] = s;
    }
    float bal = 0.f;
    for (int e = 0; e < 8; ++e)
      bal += ((float)cnt0[e] * (1.0f/KN)) * (fin[e] * (1.0f/KN));
    bal *= (float)KE;
    float zl = fin[8] * (1.0f/KN);
    out[(long)KN*KD] = 0.01f*bal + 0.001f*zl;
  }
}

// ---------------- host ----------------
extern "C" void kernel_launch(void* const* d_in, const int* in_sizes, int n_in,
                              void* d_out, int out_size, void* d_ws, size_t ws_size,
                              hipStream_t stream){
  const float* q    = (const float*)d_in[0];
  const float* k    = (const float*)d_in[1];
  const float* v    = (const float*)d_in[2];
  const float* inw  = (const float*)d_in[3];
  const float* inb  = (const float*)d_in[4];
  const float* outw = (const float*)d_in[5];
  const float* outb = (const float*)d_in[6];
  const float* ln1w = (const float*)d_in[7];
  const float* ln1b = (const float*)d_in[8];
  const float* ln2w = (const float*)d_in[9];
  const float* ln2b = (const float*)d_in[10];
  const float* rw   = (const float*)d_in[11];
  const float* w1   = (const float*)d_in[12];
  const float* b1   = (const float*)d_in[13];
  const float* w2   = (const float*)d_in[14];
  const float* b2   = (const float*)d_in[15];
  float* out = (float*)d_out;
  char* ws = (char*)d_ws;

  constexpr size_t PLB  = (size_t)KN*KD*2;            // 8,388,608 plane bytes
  constexpr long   PLE  = (long)KN*KD;                // plane elements
  constexpr size_t oW1T = 0;                          // 64 MB f16
  constexpr size_t oW2T = oW1T + 67108864;            // 64 MB f16
  constexpr size_t oWQ0 = oW2T + 67108864;            // 6 MB
  constexpr size_t oWQ1 = oWQ0 + 6291456;
  constexpr size_t oWO0 = oWQ1 + 6291456;             // 2 MB
  constexpr size_t oWO1 = oWO0 + 2097152;
  constexpr size_t oX1  = oWO1 + 2097152;             // 16 MB
  constexpr size_t oX1B = oX1  + 16777216;            // 8 MB
  constexpr size_t oMISC= oX1B + 8388608;             // 1 MB
  constexpr size_t oU1  = oMISC + 1048576;            // 84 MB: q/k/v splits -> Vtok -> ATTN+O planes -> HBUF
  constexpr size_t oU2  = oU1 + 83886080;             // 48 MB: qt/kt/vt -> xin + out_e
  constexpr size_t oU3  = oU2 + 50331648;             // 64 MB: SCF + P planes
  constexpr size_t oEND = oU3 + 67108864;             // ~361 MB
  if (ws_size < oEND) return;

  u16* W1T = (u16*)(ws + oW1T);
  u16* W2T = (u16*)(ws + oW2T);
  u16* WQ0 = (u16*)(ws + oWQ0); u16* WQ1 = (u16*)(ws + oWQ1);
  u16* WO0 = (u16*)(ws + oWO0); u16* WO1 = (u16*)(ws + oWO1);
  float* X1 = (float*)(ws + oX1);
  u16* X1B  = (u16*)(ws + oX1B);

  int*   IDX0 = (int*)(ws + oMISC);
  int*   IDX1 = (int*)(ws + oMISC + 16384);
  int*   RNK0 = (int*)(ws + oMISC + 32768);
  int*   RNK1 = (int*)(ws + oMISC + 49152);
  int*   DST0 = (int*)(ws + oMISC + 65536);
  int*   DST1 = (int*)(ws + oMISC + 81920);
  float* G0   = (float*)(ws + oMISC + 98304);
  float* G1   = (float*)(ws + oMISC + 114688);
  int*   H0   = (int*)(ws + oMISC + 131072);
  int*   H1   = (int*)(ws + oMISC + 133120);
  int*   BS0  = (int*)(ws + oMISC + 135168);
  int*   BS1  = (int*)(ws + oMISC + 137216);
  int*   CNT0 = (int*)(ws + oMISC + 139264);
  int*   SLOT = (int*)(ws + oMISC + 139776);
  float* PTOK = (float*)(ws + oMISC + 262144);
  float* LSET = (float*)(ws + oMISC + 393216);

  u16* Qs0 = (u16*)(ws + oU1);           u16* Qs1 = (u16*)(ws + oU1 + PLB);
  u16* Ks0 = (u16*)(ws + oU1 + 2*PLB);   u16* Ks1 = (u16*)(ws + oU1 + 3*PLB);
  u16* Vs0 = (u16*)(ws + oU1 + 4*PLB);   u16* Vs1 = (u16*)(ws + oU1 + 5*PLB);
  u16* VTOK0 = (u16*)(ws + oU1 + 6*PLB); u16* VTOK1 = (u16*)(ws + oU1 + 7*PLB);  // V token planes
  float* ATTN = (float*)(ws + oU1);                          // 16 MB, after splits die
  u16* O0 = (u16*)(ws + oU1 + 16777216);
  u16* O1 = (u16*)(ws + oU1 + 16777216 + PLB);
  u16* HBUF = (u16*)(ws + oU1);                              // 80 MB, after ATTN/O/VTOK die

  u16* QT0 = (u16*)(ws + oU2);           u16* QT1 = (u16*)(ws + oU2 + PLB);      // Q token planes
  u16* KT0 = (u16*)(ws + oU2 + 2*PLB);   u16* KT1 = (u16*)(ws + oU2 + 3*PLB);    // K token planes
  u16* VT0 = (u16*)(ws + oU2 + 4*PLB);   u16* VT1 = (u16*)(ws + oU2 + 5*PLB);    // V (bh,dh,S) planes
  u16* XIN  = (u16*)(ws + oU2);                              // after attention
  u16* OUTE = (u16*)(ws + oU2 + 20971520);

  float* SCF = (float*)(ws + oU3);                           // 33.5 MB fp32
  u16* PH  = (u16*)(ws + oU3 + 33554432);
  u16* PL  = (u16*)(ws + oU3 + 50331648);

  hipMemsetAsync(ws + oMISC + 139776, 0xFF, (size_t)KE*KCAP*4, stream);

  // 2-plane f16 splits (residual plane scaled x4096)
  split2k<<<4096, 256, 0, stream>>>(q, Qs0, Qs1, (long)KN*KD/4);
  split2k<<<4096, 256, 0, stream>>>(k, Ks0, Ks1, (long)KN*KD/4);
  split2k<<<4096, 256, 0, stream>>>(v, Vs0, Vs1, (long)KN*KD/4);
  split2k<<<3072, 256, 0, stream>>>(inw, WQ0, WQ1, 786432);
  split2k<<<1024, 256, 0, stream>>>(outw, WO0, WO1, 262144);

  // FFN weight transposes to (N,K) f16 for NT GEMM
  trans_b<<<dim3(KDFF/32, KD/32, KE), dim3(32,8), 0, stream>>>(w1, W1T, KD, KDFF);
  trans_b<<<dim3(KD/32, KDFF/32, KE), dim3(32,8), 0, stream>>>(w2, W2T, KDFF, KD);

  // fused QKV projections (z=0:Q, 1:K, 2:V), f16 2-plane 3-term -> token layout
  {
    GArgs ga{};
    ga.A0=Qs0; ga.A1=Qs1; ga.lda=KD; ga.sA=2*PLE;
    ga.B0=WQ0; ga.B1=WQ1; ga.ldb=KD; ga.sB=1048576;
    ga.bias=inb; ga.biasStride=KD;
    ga.o0=QT0; ga.o1=VTOK0; ga.outF=nullptr;
    ga.K=KD; ga.mode=7; ga.scale=1.f;
    gemm128<2><<<dim3(8, 32, 3), 256, 0, stream>>>(ga);
  }

  // V: token layout -> (bh, dh, S) for the PV GEMM (u16 passthrough, both planes)
  vtrans<<<dim3(KS/32, KD/32, KB), dim3(32,8), 0, stream>>>(VTOK0, VTOK1, VT0, VT1);

  // attention, chunked over bh (4 chunks of 32)
  for (int c = 0; c < KNCH; ++c){
    long hoff = (long)c * KCHB * KS * KDH;
    GArgs gs{};
    gs.A0=QT0; gs.A1=QT1; gs.lda=KD; gs.sA=0;
    gs.B0=KT0; gs.B1=KT1; gs.ldb=KD; gs.sB=0;
    gs.hbase = c*KCHB;
    gs.bias=nullptr; gs.biasStride=0; gs.outF=SCF; gs.o0=nullptr;
    gs.K=KDH; gs.mode=2; gs.scale=0.125f;
    gemm128<2><<<dim3(4, 4, KCHB), 256, 0, stream>>>(gs);

    softmax2<<<KCHB*KS, 64, 0, stream>>>(SCF, PH, PL);

    gemm_pv<<<dim3(4, KCHB), 256, 0, stream>>>(PH, PL, VT0+hoff, VT1+hoff,
                                               O0, O1, c*KCHB);
  }

  // out-projection -> ATTN fp32
  {
    GArgs go{};
    go.A0=O0; go.A1=O1; go.lda=KD; go.sA=0;
    go.B0=WO0; go.B1=WO1; go.ldb=KD; go.sB=0;
    go.bias=outb; go.biasStride=0; go.outF=ATTN; go.o0=nullptr;
    go.K=KD; go.mode=4; go.scale=1.f;
    gemm128<2><<<dim3(8, 32, 1), 256, 0, stream>>>(go);
  }

  // LN1 + router
  ln1_router<<<KN, 256, 0, stream>>>(q, ATTN, ln1w, ln1b, rw, X1, X1B,
                                     IDX0, IDX1, G0, G1, PTOK, LSET);
  // capacity-ordered routing
  scan1<<<64, 64, 0, stream>>>(IDX0, IDX1, RNK0, RNK1, H0, H1);
  scan2<<<1, 64, 0, stream>>>(H0, H1, BS0, BS1, CNT0);
  scan3<<<16, 256, 0, stream>>>(IDX0, IDX1, RNK0, RNK1, BS0, BS1, DST0, DST1, SLOT);
  aux_k<<<1, 1024, 0, stream>>>(CNT0, PTOK, LSET, out);
  gather_xin<<<KE*KCAP, 64, 0, stream>>>(SLOT, X1B, XIN);

  // expert FFN (plain f16, 1-plane)
  {
    GArgs f1{};
    f1.A0=XIN; f1.A1=nullptr; f1.lda=KD; f1.sA=(long)KCAP*KD;
    f1.B0=W1T; f1.B1=nullptr; f1.ldb=KD; f1.sB=(long)KDFF*KD;
    f1.bias=b1; f1.biasStride=KDFF; f1.outF=nullptr; f1.o0=HBUF;
    f1.K=KD; f1.mode=5; f1.scale=1.f;
    gemm128<1><<<dim3(KDFF/128, KCAP/128, KE), 256, 0, stream>>>(f1);

    GArgs f2{};
    f2.A0=HBUF; f2.A1=nullptr; f2.lda=KDFF; f2.sA=(long)KCAP*KDFF;
    f2.B0=W2T; f2.B1=nullptr; f2.ldb=KDFF; f2.sB=(long)KD*KDFF;
    f2.bias=b2; f2.biasStride=KD; f2.outF=nullptr; f2.o0=OUTE;
    f2.K=KDFF; f2.mode=6; f2.scale=1.f;
    gemm128<1><<<dim3(KD/128, KCAP/128, KE), 256, 0, stream>>>(f2);
  }

  // combine + LN2 -> output
  combine_ln2<<<KN, 256, 0, stream>>>(X1, OUTE, DST0, DST1, G0, G1, ln2w, ln2b, out);
}

// Round 6
// 1175.372 us; speedup vs baseline: 1.1497x; 1.0326x over previous
//
#include <hip/hip_runtime.h>
#include <cstdint>
#include <cstddef>

// ---------------- constants ----------------
#define KB   8
#define KS   512
#define KD   1024
#define KH   16
#define KDH  64
#define KE   8
#define KDFF 4096
#define KN   4096      // B*S tokens
#define KCAP 1280      // ceil(2*4096/8*1.25)
#define KCHB 32        // attention bh per chunk
#define KNCH 4         // 128 / KCHB
#define KPLE ((long)KN*KD)   // plane elements

typedef unsigned short u16;
typedef _Float16 f16;
typedef f16   f16x8 __attribute__((ext_vector_type(8)));
typedef float f32x4 __attribute__((ext_vector_type(4)));

#define RSCALE 4096.0f
#define RINV   2.44140625e-4f   // 1/4096

__device__ __forceinline__ u16 f2h(float f){
  f16 h = (f16)f;
  return __builtin_bit_cast(u16, h);
}
__device__ __forceinline__ float h2f(u16 u){
  f16 h = __builtin_bit_cast(f16, u);
  return (float)h;
}
// 2-plane f16 split; residual plane pre-scaled x4096 so it stays in f16
// normal range (guards against possible MFMA denorm-input flush).
__device__ __forceinline__ void split2v(float f, u16 &a, u16 &b){
  f16 h0 = (f16)f;
  float r = (f - (float)h0) * RSCALE;
  a = __builtin_bit_cast(u16, h0);
  b = f2h(r);
}
__device__ __forceinline__ f16x8 ld8h(const u16* p){
  uint4 v = *(const uint4*)p;
  return __builtin_bit_cast(f16x8, v);
}
// async global->LDS, 16B per lane; lds ptr must be wave-uniform (HW adds lane*16)
__device__ __forceinline__ void async16(const u16* g, u16* l){
  __builtin_amdgcn_global_load_lds(
      (const __attribute__((address_space(1))) unsigned int*)(g),
      (__attribute__((address_space(3))) unsigned int*)(l),
      16, 0, 0);
}

// bijective XCD-aware remap (m204): dispatch id -> work id so each XCD
// gets a contiguous chunk of the grid (per-XCD L2 locality).
__device__ __forceinline__ int xcd_remap(int lin, int nwg){
  int qq = nwg >> 3, r8 = nwg & 7;
  int xcd = lin & 7, pos = lin >> 3;
  return (xcd < r8 ? xcd*(qq+1) : r8*(qq+1) + (xcd-r8)*qq) + pos;
}

struct GArgs {
  const u16 *A0, *A1;
  const u16 *B0, *B1;
  long lda, sA, ldb, sB;         // element strides
  const float* bias; long biasStride;
  float* outF;
  u16 *o0;
  u16 *o1;                       // mode 7: V token-plane base
  int K, mode;
  int hbase;                     // mode 2: chunk base bh
  float scale;
};

// ---------------- 128x128 4-wave GEMM, LDS double-buffered 2-phase ----------
// NP=2: A,B are (main, residual*4096) f16 planes; 3-term product ~ fp32 accuracy.
// T3 minimal 2-phase pipeline — STAGE(next buf) issued BEFORE COMPUTE(cur),
// __syncthreads() (vmcnt(0)+lgkmcnt(0)+s_barrier) as the per-K-step drain.
template<int NP>
__launch_bounds__(256)
__global__ void gemm128(GArgs g){
  constexpr int BUF = NP*2*4096;              // u16 elements per LDS buffer
  __shared__ __align__(16) u16 sm[2*BUF];
  const int tid  = threadIdx.x;
  const int lane = tid & 63;
  const int wave = tid >> 6;
  const int quad = lane >> 4;
  const int r    = lane & 15;
  const int wm = (wave & 1) * 64;
  const int wn = (wave >> 1) * 64;
  // XCD-aware block remap (all grids here are multiples of 8)
  const int gx = gridDim.x, gy = gridDim.y;
  const int nwg = gx*gy*(int)gridDim.z;
  int lin = (int)blockIdx.x + gx*((int)blockIdx.y + gy*(int)blockIdx.z);
  lin = xcd_remap(lin, nwg);
  const int bx = lin % gx;
  const int byy = (lin / gx) % gy;
  const int z  = lin / (gx*gy);
  const long m0 = (long)byy * 128;
  const long n0 = (long)bx * 128;
  const u16* Ap[NP]; const u16* Bp[NP];
  if (g.mode == 2){
    // token-layout heads: offset = (b)*KS*KD + h*KDH
    int bh = g.hbase + z;
    long off = ((long)(bh >> 4)*KS)*KD + (long)(bh & 15)*KDH;
    Ap[0] = g.A0 + off; Bp[0] = g.B0 + off;
    if (NP == 2){ Ap[1] = g.A1 + off; Bp[1] = g.B1 + off; }
  } else {
    Ap[0] = g.A0 + (long)z*g.sA; Bp[0] = g.B0 + (long)z*g.sB;
    if (NP == 2){ Ap[1] = g.A1 + (long)z*g.sA; Bp[1] = g.B1 + (long)z*g.sB; }
  }
  const int srow   = tid >> 2;
  const int schunk = (tid & 3) ^ ((tid >> 3) & 3);
  f32x4 acc[4][4] = {};
  f32x4 accr[4][4] = {};          // cross-term accumulator (NP==2 only; elided otherwise)

  auto STAGE = [&](int buf, int kt){
#pragma unroll
    for (int p = 0; p < NP; ++p){
#pragma unroll
      for (int r0 = 0; r0 < 2; ++r0){
        long row = r0*64 + srow;
        async16(Ap[p] + (m0 + row)*g.lda + kt + schunk*8, &sm[buf + p*4096      + r0*2048 + wave*512]);
        async16(Bp[p] + (n0 + row)*g.ldb + kt + schunk*8, &sm[buf + (NP+p)*4096 + r0*2048 + wave*512]);
      }
    }
  };
  auto COMPUTE = [&](int buf){
    f16x8 af[NP][4], bf[NP][4];
#pragma unroll
    for (int i = 0; i < 4; ++i){
      int row = wm + i*16 + r;
      int slot = quad ^ ((row >> 1) & 3);
#pragma unroll
      for (int p = 0; p < NP; ++p)
        af[p][i] = ld8h(&sm[buf + p*4096 + row*32 + slot*8]);
    }
#pragma unroll
    for (int j = 0; j < 4; ++j){
      int row = wn + j*16 + r;
      int slot = quad ^ ((row >> 1) & 3);
#pragma unroll
      for (int p = 0; p < NP; ++p)
        bf[p][j] = ld8h(&sm[buf + (NP+p)*4096 + row*32 + slot*8]);
    }
#pragma unroll
    for (int i = 0; i < 4; ++i)
#pragma unroll
      for (int j = 0; j < 4; ++j){
        acc[i][j] = __builtin_amdgcn_mfma_f32_16x16x32_f16(af[0][i], bf[0][j], acc[i][j], 0, 0, 0);
        if (NP == 2){
          accr[i][j] = __builtin_amdgcn_mfma_f32_16x16x32_f16(af[0][i], bf[1][j], accr[i][j], 0, 0, 0);
          accr[i][j] = __builtin_amdgcn_mfma_f32_16x16x32_f16(af[1][i], bf[0][j], accr[i][j], 0, 0, 0);
        }
      }
  };

  const int nk = g.K >> 5;        // always even (K in {64,512,1024,4096})
  STAGE(0, 0);
  __syncthreads();
  for (int it = 0; it < nk - 2; it += 2){
    STAGE(BUF, (it+1) << 5);
    COMPUTE(0);
    __syncthreads();
    STAGE(0, (it+2) << 5);
    COMPUTE(BUF);
    __syncthreads();
  }
  STAGE(BUF, (nk-1) << 5);
  COMPUTE(0);
  __syncthreads();
  COMPUTE(BUF);

  // epilogue: C/D layout col=lane&15, row=quad*4+reg
#pragma unroll
  for (int i = 0; i < 4; ++i){
#pragma unroll
    for (int rr = 0; rr < 4; ++rr){
      long row = m0 + wm + i*16 + quad*4 + rr;
#pragma unroll
      for (int j = 0; j < 4; ++j){
        long col = n0 + wn + j*16 + r;
        float v = acc[i][j][rr];
        if (NP == 2) v += accr[i][j][rr] * RINV;
        switch (g.mode){
          case 2: {               // scores (scaled, fp32)
            g.outF[((long)z*KS + row)*KS + col] = v * g.scale;
            break;
          }
          case 4: {               // out-proj: +bias, fp32
            v += g.bias[col];
            g.outF[row*KD + col] = v;
            break;
          }
          case 5: {               // FFN1: +b1, gelu(tanh approx), f16
            v += g.bias[(long)z*g.biasStride + col];
            float u = v + 0.044715f*v*v*v;
            v = 0.5f*v*(1.0f + tanhf(0.7978845608028654f*u));
            g.o0[((long)z*KCAP + row)*KDFF + col] = f2h(v);
            break;
          }
          case 6: {               // FFN2: +b2, f16
            v += g.bias[(long)z*g.biasStride + col];
            g.o0[((long)z*KCAP + row)*KD + col] = f2h(v);
            break;
          }
          default: {              // mode 7: fused QKV -> TOKEN layout, 2-plane split
            v += g.bias[(long)z*g.biasStride + col];
            u16* d0 = (z < 2) ? (g.o0 + (long)z*2*KPLE) : g.o1;
            u16* d1 = d0 + KPLE;
            long idx = row*KD + col;
            unsigned short x, y; split2v(v, x, y);
            d0[idx] = x; d1[idx] = y;
            break;
          }
        }
      }
    }
  }
}

// ---------------- 128x64 4-wave GEMM for QKV / out-proj (R6 bisect) ---------
// acc[4][2] halves accumulator VGPRs vs gemm128 (~130 total): natural 3+
// waves/SIMD without forcing; LDS 48KB dbuf -> 3 blocks/CU. No min-waves
// launch_bounds arg (R4 suspect removed). Modes 4 and 7 only.
template<int NP>
__launch_bounds__(256)
__global__ void gemm64(GArgs g){
  constexpr int BUF = NP*4096 + NP*2048;      // A: NP*128x32, B: NP*64x32 (u16)
  __shared__ __align__(16) u16 sm[2*BUF];
  const int tid  = threadIdx.x;
  const int lane = tid & 63;
  const int wave = tid >> 6;
  const int quad = lane >> 4;
  const int r    = lane & 15;
  const int wm = (wave & 1) * 64;
  const int wn = (wave >> 1) * 32;
  const int gx = gridDim.x, gy = gridDim.y;
  const int nwg = gx*gy*(int)gridDim.z;
  int lin = (int)blockIdx.x + gx*((int)blockIdx.y + gy*(int)blockIdx.z);
  lin = xcd_remap(lin, nwg);
  const int bx = lin % gx;
  const int byy = (lin / gx) % gy;
  const int z  = lin / (gx*gy);
  const long m0 = (long)byy * 128;
  const long n0 = (long)bx * 64;
  const u16* Ap[NP]; const u16* Bp[NP];
  Ap[0] = g.A0 + (long)z*g.sA; Bp[0] = g.B0 + (long)z*g.sB;
  if (NP == 2){ Ap[1] = g.A1 + (long)z*g.sA; Bp[1] = g.B1 + (long)z*g.sB; }
  const int srow   = tid >> 2;
  const int schunk = (tid & 3) ^ ((tid >> 3) & 3);
  f32x4 acc[4][2] = {};
  f32x4 accr[4][2] = {};

  auto STAGE = [&](int buf, int kt){
#pragma unroll
    for (int p = 0; p < NP; ++p){
#pragma unroll
      for (int r0 = 0; r0 < 2; ++r0){
        long row = r0*64 + srow;
        async16(Ap[p] + (m0 + row)*g.lda + kt + schunk*8, &sm[buf + p*4096 + r0*2048 + wave*512]);
      }
      async16(Bp[p] + (n0 + srow)*g.ldb + kt + schunk*8, &sm[buf + NP*4096 + p*2048 + wave*512]);
    }
  };
  auto COMPUTE = [&](int buf){
    f16x8 af[NP][4], bf[NP][2];
#pragma unroll
    for (int i = 0; i < 4; ++i){
      int row = wm + i*16 + r;
      int slot = quad ^ ((row >> 1) & 3);
#pragma unroll
      for (int p = 0; p < NP; ++p)
        af[p][i] = ld8h(&sm[buf + p*4096 + row*32 + slot*8]);
    }
#pragma unroll
    for (int j = 0; j < 2; ++j){
      int row = wn + j*16 + r;
      int slot = quad ^ ((row >> 1) & 3);
#pragma unroll
      for (int p = 0; p < NP; ++p)
        bf[p][j] = ld8h(&sm[buf + NP*4096 + p*2048 + row*32 + slot*8]);
    }
#pragma unroll
    for (int i = 0; i < 4; ++i)
#pragma unroll
      for (int j = 0; j < 2; ++j){
        acc[i][j] = __builtin_amdgcn_mfma_f32_16x16x32_f16(af[0][i], bf[0][j], acc[i][j], 0, 0, 0);
        if (NP == 2){
          accr[i][j] = __builtin_amdgcn_mfma_f32_16x16x32_f16(af[0][i], bf[1][j], accr[i][j], 0, 0, 0);
          accr[i][j] = __builtin_amdgcn_mfma_f32_16x16x32_f16(af[1][i], bf[0][j], accr[i][j], 0, 0, 0);
        }
      }
  };

  const int nk = g.K >> 5;
  STAGE(0, 0);
  __syncthreads();
  for (int it = 0; it < nk - 2; it += 2){
    STAGE(BUF, (it+1) << 5);
    COMPUTE(0);
    __syncthreads();
    STAGE(0, (it+2) << 5);
    COMPUTE(BUF);
    __syncthreads();
  }
  STAGE(BUF, (nk-1) << 5);
  COMPUTE(0);
  __syncthreads();
  COMPUTE(BUF);

#pragma unroll
  for (int i = 0; i < 4; ++i){
#pragma unroll
    for (int rr = 0; rr < 4; ++rr){
      long row = m0 + wm + i*16 + quad*4 + rr;
#pragma unroll
      for (int j = 0; j < 2; ++j){
        long col = n0 + wn + j*16 + r;
        float v = acc[i][j][rr];
        if (NP == 2) v += accr[i][j][rr] * RINV;
        if (g.mode == 4){         // out-proj: +bias, fp32
          v += g.bias[col];
          g.outF[row*KD + col] = v;
        } else {                  // mode 7: fused QKV -> TOKEN layout, 2-plane split
          v += g.bias[(long)z*g.biasStride + col];
          u16* d0 = (z < 2) ? (g.o0 + (long)z*2*KPLE) : g.o1;
          u16* d1 = d0 + KPLE;
          long idx = row*KD + col;
          unsigned short x, y; split2v(v, x, y);
          d0[idx] = x; d1[idx] = y;
        }
      }
    }
  }
}

// ---------------- PV GEMM: per bh, O[512,64] = P[512,512] @ Vt[64,512]^T ---------
// Block tile 128x64, 4 waves as 2(M)x2(N of 32); f16 2-plane 3-term.
// Chunked (R3 layout), race-free 2-phase double-buffer.
__launch_bounds__(256)
__global__ void gemm_pv(const u16* __restrict__ Ph, const u16* __restrict__ Pl,
                        const u16* __restrict__ V0, const u16* __restrict__ V1,
                        u16* __restrict__ O0, u16* __restrict__ O1, int chunkBase){
  constexpr int BUF = 2*4096 + 2*2048;                // 12288 u16 = 24 KB
  __shared__ __align__(16) u16 sm[2*BUF];             // 48 KB
  const int tid  = threadIdx.x;
  const int lane = tid & 63;
  const int wave = tid >> 6;
  const int quad = lane >> 4;
  const int r    = lane & 15;
  const int wm = (wave & 1) * 64;
  const int wn = (wave >> 1) * 32;
  const int gx = gridDim.x;
  const int nwg = gx*(int)gridDim.y;
  int lin = (int)blockIdx.x + gx*(int)blockIdx.y;
  lin = xcd_remap(lin, nwg);
  const int z  = lin / gx;
  const long m0 = (long)(lin % gx) * 128;
  const u16* Ap[2] = { Ph + (long)z*KS*KS,  Pl + (long)z*KS*KS };
  const u16* Bp[2] = { V0 + (long)z*KDH*KS, V1 + (long)z*KDH*KS };
  const int srow   = tid >> 2;
  const int schunk = (tid & 3) ^ ((tid >> 3) & 3);
  f32x4 acc[4][2] = {};
  f32x4 accr[4][2] = {};

  auto STAGE = [&](int buf, int kt){
#pragma unroll
    for (int p = 0; p < 2; ++p){
#pragma unroll
      for (int r0 = 0; r0 < 2; ++r0){
        long row = r0*64 + srow;
        async16(Ap[p] + (m0 + row)*KS + kt + schunk*8, &sm[buf + p*4096 + r0*2048 + wave*512]);
      }
      async16(Bp[p] + srow*KS + kt + schunk*8, &sm[buf + 8192 + p*2048 + wave*512]);
    }
  };
  auto COMPUTE = [&](int buf){
    f16x8 af[2][4], bf[2][2];
#pragma unroll
    for (int i = 0; i < 4; ++i){
      int row = wm + i*16 + r;
      int slot = quad ^ ((row >> 1) & 3);
#pragma unroll
      for (int p = 0; p < 2; ++p)
        af[p][i] = ld8h(&sm[buf + p*4096 + row*32 + slot*8]);
    }
#pragma unroll
    for (int j = 0; j < 2; ++j){
      int row = wn + j*16 + r;
      int slot = quad ^ ((row >> 1) & 3);
#pragma unroll
      for (int p = 0; p < 2; ++p)
        bf[p][j] = ld8h(&sm[buf + 8192 + p*2048 + row*32 + slot*8]);
    }
#pragma unroll
    for (int i = 0; i < 4; ++i)
#pragma unroll
      for (int j = 0; j < 2; ++j){
        acc[i][j]  = __builtin_amdgcn_mfma_f32_16x16x32_f16(af[0][i], bf[0][j], acc[i][j], 0, 0, 0);
        accr[i][j] = __builtin_amdgcn_mfma_f32_16x16x32_f16(af[0][i], bf[1][j], accr[i][j], 0, 0, 0);
        accr[i][j] = __builtin_amdgcn_mfma_f32_16x16x32_f16(af[1][i], bf[0][j], accr[i][j], 0, 0, 0);
      }
  };

  const int nk = KS >> 5;   // 16
  STAGE(0, 0);
  __syncthreads();
  for (int it = 0; it < nk - 2; it += 2){
    STAGE(BUF, (it+1) << 5);
    COMPUTE(0);
    __syncthreads();
    STAGE(0, (it+2) << 5);
    COMPUTE(BUF);
    __syncthreads();
  }
  STAGE(BUF, (nk-1) << 5);
  COMPUTE(0);
  __syncthreads();
  COMPUTE(BUF);

  int bh = chunkBase + z;
  long b = bh >> 4, h = bh & 15;
#pragma unroll
  for (int i = 0; i < 4; ++i){
#pragma unroll
    for (int rr = 0; rr < 4; ++rr){
      long s = m0 + wm + i*16 + quad*4 + rr;
#pragma unroll
      for (int j = 0; j < 2; ++j){
        long col = wn + j*16 + r;
        float v = acc[i][j][rr] + accr[i][j][rr] * RINV;
        long idx = (b*KS + s)*KD + h*KDH + col;
        unsigned short x, y; split2v(v, x, y);
        O0[idx] = x; O1[idx] = y;
      }
    }
  }
}

// ---------------- prep kernels ----------------
__global__ void split2k(const float* __restrict__ x, u16* __restrict__ h,
                        u16* __restrict__ l, long n4){
  long i = (long)blockIdx.x*blockDim.x + threadIdx.x;
  if (i >= n4) return;
  float4 v = ((const float4*)x)[i];
  ushort4 a, b;
  split2v(v.x, a.x, b.x);
  split2v(v.y, a.y, b.y);
  split2v(v.z, a.z, b.z);
  split2v(v.w, a.w, b.w);
  ((ushort4*)h)[i] = a; ((ushort4*)l)[i] = b;
}

// batched transpose: in (z,R,C) f32 -> out (z,C,R) f16
__global__ void trans_b(const float* __restrict__ in, u16* __restrict__ outp, int R, int Cc){
  __shared__ float tile[32][33];
  long z = blockIdx.z;
  const float* ip = in + z*(long)R*Cc;
  u16* op = outp + z*(long)R*Cc;
  int c0 = blockIdx.x*32, r0 = blockIdx.y*32;
  int tx = threadIdx.x, ty = threadIdx.y;
  for (int rr = ty; rr < 32; rr += 8)
    tile[rr][tx] = ip[(long)(r0+rr)*Cc + c0 + tx];
  __syncthreads();
  for (int cc = ty; cc < 32; cc += 8)
    op[(long)(c0+cc)*R + r0 + tx] = f2h(tile[tx][cc]);
}

// V token-plane (token, 1024) u16 -> head-transposed (bh, dh, S) u16, both planes.
__global__ void vtrans(const u16* __restrict__ in0, const u16* __restrict__ in1,
                       u16* __restrict__ out0, u16* __restrict__ out1){
  __shared__ u16 tile[2][32][33];
  int sT = blockIdx.x;       // 0..15  (s tile within b)
  int dT = blockIdx.y;       // 0..31  (global feature tile)
  int b  = blockIdx.z;       // 0..7
  int tx = threadIdx.x;      // 0..31
  int ty = threadIdx.y;      // 0..7
  long srow = (long)b*KS + sT*32;
  int d0 = dT*32;
  for (int rr = ty; rr < 32; rr += 8){
    tile[0][rr][tx] = in0[(srow+rr)*KD + d0 + tx];
    tile[1][rr][tx] = in1[(srow+rr)*KD + d0 + tx];
  }
  __syncthreads();
  int h = d0 >> 6;           // constant per block (d0 multiple of 32)
  int dbase = d0 & 63;
  long obase = ((long)(b*KH + h)*KDH)*KS + sT*32 + tx;
  for (int cc = ty; cc < 32; cc += 8){
    long o = obase + (long)(dbase+cc)*KS;
    out0[o] = tile[0][tx][cc];
    out1[o] = tile[1][tx][cc];
  }
}

// ---------------- softmax over 512-wide rows -> 2-plane f16 P ----------------
__launch_bounds__(64)
__global__ void softmax2(const float* __restrict__ scores, u16* __restrict__ ph,
                         u16* __restrict__ pl){
  long row = blockIdx.x;
  const float* rp = scores + row * KS;
  int lane = threadIdx.x;
  float4 a = ((const float4*)rp)[lane*2];
  float4 b = ((const float4*)rp)[lane*2 + 1];
  float vv[8] = {a.x,a.y,a.z,a.w,b.x,b.y,b.z,b.w};
  float m = vv[0];
#pragma unroll
  for (int t = 1; t < 8; ++t) m = fmaxf(m, vv[t]);
  for (int off = 32; off; off >>= 1) m = fmaxf(m, __shfl_xor(m, off));
  float s = 0.f;
#pragma unroll
  for (int t = 0; t < 8; ++t){ vv[t] = expf(vv[t] - m); s += vv[t]; }
  for (int off = 32; off; off >>= 1) s += __shfl_xor(s, off);
  float inv = 1.0f / s;
  unsigned short hh[8], ll[8];
#pragma unroll
  for (int t = 0; t < 8; ++t) split2v(vv[t] * inv, hh[t], ll[t]);
  ushort4* dh = (ushort4*)(ph + row*KS + lane*8);
  dh[0] = make_ushort4(hh[0],hh[1],hh[2],hh[3]);
  dh[1] = make_ushort4(hh[4],hh[5],hh[6],hh[7]);
  ushort4* dl = (ushort4*)(pl + row*KS + lane*8);
  dl[0] = make_ushort4(ll[0],ll[1],ll[2],ll[3]);
  dl[1] = make_ushort4(ll[4],ll[5],ll[6],ll[7]);
}

// ---------------- LN1 + router (fp32 exact; no contended atomics) ----------------
__launch_bounds__(256)
__global__ void ln1_router(const float* __restrict__ q, const float* __restrict__ attn,
    const float* __restrict__ lnw, const float* __restrict__ lnb, const float* __restrict__ rw,
    float* __restrict__ x1, u16* __restrict__ x1b,
    int* __restrict__ idx0, int* __restrict__ idx1, float* __restrict__ gate0, float* __restrict__ gate1,
    float* __restrict__ ptok, float* __restrict__ lset){
  const int t = blockIdx.x, tid = threadIdx.x;
  const int lane = tid & 63, wid = tid >> 6;
  float4 xv = ((const float4*)(q    + (long)t*KD))[tid];
  float4 av = ((const float4*)(attn + (long)t*KD))[tid];
  xv.x += av.x; xv.y += av.y; xv.z += av.z; xv.w += av.w;
  float s  = xv.x + xv.y + xv.z + xv.w;
  float ss = xv.x*xv.x + xv.y*xv.y + xv.z*xv.z + xv.w*xv.w;
  for (int off = 32; off; off >>= 1){ s += __shfl_xor(s, off); ss += __shfl_xor(ss, off); }
  __shared__ float rs[4], rss[4];
  if (lane == 0){ rs[wid] = s; rss[wid] = ss; }
  __syncthreads();
  float S1 = rs[0]+rs[1]+rs[2]+rs[3];
  float S2 = rss[0]+rss[1]+rss[2]+rss[3];
  float mean = S1 * (1.0f/KD);
  float var  = S2 * (1.0f/KD) - mean*mean;
  float rstd = rsqrtf(var + 1e-5f);
  float4 w4 = ((const float4*)lnw)[tid];
  float4 b4 = ((const float4*)lnb)[tid];
  float y0 = (xv.x - mean)*rstd*w4.x + b4.x;
  float y1 = (xv.y - mean)*rstd*w4.y + b4.y;
  float y2 = (xv.z - mean)*rstd*w4.z + b4.z;
  float y3 = (xv.w - mean)*rstd*w4.w + b4.w;
  float4 yo; yo.x=y0; yo.y=y1; yo.z=y2; yo.w=y3;
  ((float4*)(x1 + (long)t*KD))[tid] = yo;
  ushort4 yb; yb.x=f2h(y0); yb.y=f2h(y1); yb.z=f2h(y2); yb.w=f2h(y3);
  ((ushort4*)(x1b + (long)t*KD))[tid] = yb;
  int d0 = tid*4;
  float rloc[4][8];
#pragma unroll
  for (int c = 0; c < 4; ++c){
    const float4* rp = (const float4*)(rw + (long)(d0 + c)*KE);
    float4 u = rp[0], v2 = rp[1];
    rloc[c][0]=u.x; rloc[c][1]=u.y; rloc[c][2]=u.z; rloc[c][3]=u.w;
    rloc[c][4]=v2.x; rloc[c][5]=v2.y; rloc[c][6]=v2.z; rloc[c][7]=v2.w;
  }
  float yv[4] = {y0,y1,y2,y3};
  float pr[8];
#pragma unroll
  for (int e = 0; e < 8; ++e)
    pr[e] = yv[0]*rloc[0][e] + yv[1]*rloc[1][e] + yv[2]*rloc[2][e] + yv[3]*rloc[3][e];
#pragma unroll
  for (int e = 0; e < 8; ++e)
    for (int off = 32; off; off >>= 1) pr[e] += __shfl_xor(pr[e], off);
  __shared__ float wl[4][8];
  if (lane == 0)
#pragma unroll
    for (int e = 0; e < 8; ++e) wl[wid][e] = pr[e];
  __syncthreads();
  if (tid == 0){
    float lg[8];
#pragma unroll
    for (int e = 0; e < 8; ++e) lg[e] = wl[0][e]+wl[1][e]+wl[2][e]+wl[3][e];
    float mx = lg[0];
    for (int e = 1; e < 8; ++e) mx = fmaxf(mx, lg[e]);
    float pe[8], se = 0.f;
    for (int e = 0; e < 8; ++e){ pe[e] = expf(lg[e]-mx); se += pe[e]; }
    float inv = 1.0f/se;
    for (int e = 0; e < 8; ++e) pe[e] *= inv;
    int e0 = 0;
    for (int e = 1; e < 8; ++e) if (pe[e] > pe[e0]) e0 = e;   // first-index tie break (jax)
    int e1 = (e0 == 0) ? 1 : 0;
    for (int e = 0; e < 8; ++e) if (e != e0 && pe[e] > pe[e1]) e1 = e;
    idx0[t] = e0; idx1[t] = e1;
    gate0[t] = pe[e0]; gate1[t] = pe[e1];
    for (int e = 0; e < 8; ++e) ptok[(long)t*8 + e] = pe[e];
    lset[t] = mx + logf(se);
  }
}

// ---------------- routing scans ----------------
__launch_bounds__(64)
__global__ void scan1(const int* __restrict__ idx0, const int* __restrict__ idx1,
                      int* __restrict__ rnk0, int* __restrict__ rnk1,
                      int* __restrict__ h0, int* __restrict__ h1){
  int lane = threadIdx.x;
  int t = blockIdx.x*64 + lane;
  int i0 = idx0[t], i1 = idx1[t];
  unsigned long long below = (1ull << lane) - 1ull;
  unsigned long long b0[8], b1[8];
#pragma unroll
  for (int e = 0; e < 8; ++e){
    b0[e] = __ballot(i0 == e);
    b1[e] = __ballot(i1 == e);
  }
  rnk0[t] = __popcll(b0[i0] & below);
  rnk1[t] = __popcll(b1[i1] & below);
  if (lane < 8){
    h0[blockIdx.x*8 + lane] = __popcll(b0[lane]);
    h1[blockIdx.x*8 + lane] = __popcll(b1[lane]);
  }
}

__launch_bounds__(64)
__global__ void scan2(const int* __restrict__ h0, const int* __restrict__ h1,
                      int* __restrict__ bs0, int* __restrict__ bs1, int* __restrict__ cnt0){
  int lane = threadIdx.x;  // lane = chunk id (64 chunks)
  for (int e = 0; e < 8; ++e){
    int v = h0[lane*8 + e];
    int x = v;
    for (int off = 1; off < 64; off <<= 1){
      int y = __shfl_up(x, off);
      if (lane >= off) x += y;
    }
    bs0[lane*8 + e] = x - v;
    int tot = __shfl(x, 63);
    if (lane == 0) cnt0[e] = tot;
    int w = h1[lane*8 + e];
    int xx = w;
    for (int off = 1; off < 64; off <<= 1){
      int y = __shfl_up(xx, off);
      if (lane >= off) xx += y;
    }
    bs1[lane*8 + e] = tot + xx - w;
  }
}

__global__ void scan3(const int* __restrict__ idx0, const int* __restrict__ idx1,
                      const int* __restrict__ rnk0, const int* __restrict__ rnk1,
                      const int* __restrict__ bs0, const int* __restrict__ bs1,
                      int* __restrict__ dst0, int* __restrict__ dst1, int* __restrict__ slot){
  int t = blockIdx.x*blockDim.x + threadIdx.x;
  if (t >= KN) return;
  int c = t >> 6;
  int e0 = idx0[t], e1 = idx1[t];
  int p0 = bs0[c*8 + e0] + rnk0[t];
  int p1 = bs1[c*8 + e1] + rnk1[t];
  int d0 = (p0 < KCAP) ? (e0*KCAP + p0) : -1;
  int d1 = (p1 < KCAP) ? (e1*KCAP + p1) : -1;
  dst0[t] = d0; dst1[t] = d1;
  if (d0 >= 0) slot[d0] = t;
  if (d1 >= 0) slot[d1] = t;
}

// ---------------- gather xin ----------------
__launch_bounds__(64)
__global__ void gather_xin(const int* __restrict__ slot_token, const u16* __restrict__ x1b,
                           u16* __restrict__ xin){
  long slot = blockIdx.x;
  int t = slot_token[slot];
  uint4* dst = (uint4*)(xin + slot*KD);
  int lane = threadIdx.x;
  if (t >= 0){
    const uint4* src = (const uint4*)(x1b + (long)t*KD);
    dst[lane*2]   = src[lane*2];
    dst[lane*2+1] = src[lane*2+1];
  } else {
    uint4 zz; zz.x = zz.y = zz.z = zz.w = 0;
    dst[lane*2] = zz; dst[lane*2+1] = zz;
  }
}

// ---------------- combine + LN2 -> output ----------------
__launch_bounds__(256)
__global__ void combine_ln2(const float* __restrict__ x1, const u16* __restrict__ oute,
    const int* __restrict__ dest0, const int* __restrict__ dest1,
    const float* __restrict__ gate0, const float* __restrict__ gate1,
    const float* __restrict__ lnw, const float* __restrict__ lnb, float* __restrict__ out){
  const int t = blockIdx.x, tid = threadIdx.x;
  const int lane = tid & 63, wid = tid >> 6;
  float4 xv = ((const float4*)(x1 + (long)t*KD))[tid];
  int d0 = dest0[t], d1 = dest1[t];
  float g0 = gate0[t], g1 = gate1[t];
  if (d0 >= 0){
    ushort4 o = ((const ushort4*)(oute + (long)d0*KD))[tid];
    xv.x += g0*h2f(o.x); xv.y += g0*h2f(o.y); xv.z += g0*h2f(o.z); xv.w += g0*h2f(o.w);
  }
  if (d1 >= 0){
    ushort4 o = ((const ushort4*)(oute + (long)d1*KD))[tid];
    xv.x += g1*h2f(o.x); xv.y += g1*h2f(o.y); xv.z += g1*h2f(o.z); xv.w += g1*h2f(o.w);
  }
  float s  = xv.x + xv.y + xv.z + xv.w;
  float ss = xv.x*xv.x + xv.y*xv.y + xv.z*xv.z + xv.w*xv.w;
  for (int off = 32; off; off >>= 1){ s += __shfl_xor(s, off); ss += __shfl_xor(ss, off); }
  __shared__ float rs[4], rss[4];
  if (lane == 0){ rs[wid] = s; rss[wid] = ss; }
  __syncthreads();
  float S1 = rs[0]+rs[1]+rs[2]+rs[3];
  float S2 = rss[0]+rss[1]+rss[2]+rss[3];
  float mean = S1 * (1.0f/KD);
  float var  = S2 * (1.0f/KD) - mean*mean;
  float rstd = rsqrtf(var + 1e-5f);
  float4 w4 = ((const float4*)lnw)[tid];
  float4 b4 = ((const float4*)lnb)[tid];
  float4 yo;
  yo.x = (xv.x - mean)*rstd*w4.x + b4.x;
  yo.y = (xv.y - mean)*rstd*w4.y + b4.y;
  yo.z = (xv.z - mean)*rstd*w4.z + b4.z;
  yo.w = (xv.w - mean)*rstd*w4.w + b4.w;
  ((float4*)(out + (long)t*KD))[tid] = yo;
}

// ---------------- aux: tree-reduce per-token probs + lse^2 ----------------
__launch_bounds__(1024)
__global__ void aux_k(const int* __restrict__ cnt0, const float* __restrict__ ptok,
                      const float* __restrict__ lset, float* __restrict__ out){
  int t = threadIdx.x;
  float ps[8] = {0,0,0,0,0,0,0,0};
  float l2 = 0.f;
  for (int i = t; i < KN; i += 1024){
    const float4* p = (const float4*)(ptok + (long)i*8);
    float4 a = p[0], b = p[1];
    ps[0]+=a.x; ps[1]+=a.y; ps[2]+=a.z; ps[3]+=a.w;
    ps[4]+=b.x; ps[5]+=b.y; ps[6]+=b.z; ps[7]+=b.w;
    float l = lset[i]; l2 = fmaf(l, l, l2);
  }
#pragma unroll
  for (int off = 32; off; off >>= 1){
#pragma unroll
    for (int e = 0; e < 8; ++e) ps[e] += __shfl_xor(ps[e], off);
    l2 += __shfl_xor(l2, off);
  }
  __shared__ float sp[16][9];
  int lane = t & 63, wid = t >> 6;
  if (lane == 0){
#pragma unroll
    for (int e = 0; e < 8; ++e) sp[wid][e] = ps[e];
    sp[wid][8] = l2;
  }
  __syncthreads();
  if (t == 0){
    float fin[9];
#pragma unroll
    for (int j = 0; j < 9; ++j){
      float s = 0.f;
      for (int w2 = 0; w2 < 16; ++w2) s += sp[w2][j];
      fin[j] = s;
    }
    float bal = 0.f;
    for (int e = 0; e < 8; ++e)
      bal += ((float)cnt0[e] * (1.0f/KN)) * (fin[e] * (1.0f/KN));
    bal *= (float)KE;
    float zl = fin[8] * (1.0f/KN);
    out[(long)KN*KD] = 0.01f*bal + 0.001f*zl;
  }
}

// ---------------- host ----------------
extern "C" void kernel_launch(void* const* d_in, const int* in_sizes, int n_in,
                              void* d_out, int out_size, void* d_ws, size_t ws_size,
                              hipStream_t stream){
  const float* q    = (const float*)d_in[0];
  const float* k    = (const float*)d_in[1];
  const float* v    = (const float*)d_in[2];
  const float* inw  = (const float*)d_in[3];
  const float* inb  = (const float*)d_in[4];
  const float* outw = (const float*)d_in[5];
  const float* outb = (const float*)d_in[6];
  const float* ln1w = (const float*)d_in[7];
  const float* ln1b = (const float*)d_in[8];
  const float* ln2w = (const float*)d_in[9];
  const float* ln2b = (const float*)d_in[10];
  const float* rw   = (const float*)d_in[11];
  const float* w1   = (const float*)d_in[12];
  const float* b1   = (const float*)d_in[13];
  const float* w2   = (const float*)d_in[14];
  const float* b2   = (const float*)d_in[15];
  float* out = (float*)d_out;
  char* ws = (char*)d_ws;

  constexpr size_t PLB  = (size_t)KN*KD*2;            // 8,388,608 plane bytes
  constexpr long   PLE  = (long)KN*KD;                // plane elements
  constexpr size_t oW1T = 0;                          // 64 MB f16
  constexpr size_t oW2T = oW1T + 67108864;            // 64 MB f16
  constexpr size_t oWQ0 = oW2T + 67108864;            // 6 MB
  constexpr size_t oWQ1 = oWQ0 + 6291456;
  constexpr size_t oWO0 = oWQ1 + 6291456;             // 2 MB
  constexpr size_t oWO1 = oWO0 + 2097152;
  constexpr size_t oX1  = oWO1 + 2097152;             // 16 MB
  constexpr size_t oX1B = oX1  + 16777216;            // 8 MB
  constexpr size_t oMISC= oX1B + 8388608;             // 1 MB
  constexpr size_t oU1  = oMISC + 1048576;            // 84 MB: q/k/v splits -> Vtok -> ATTN+O planes -> HBUF
  constexpr size_t oU2  = oU1 + 83886080;             // 48 MB: qt/kt/vt -> xin + out_e
  constexpr size_t oU3  = oU2 + 50331648;             // 64 MB: SCF + P planes
  constexpr size_t oEND = oU3 + 67108864;             // ~361 MB
  if (ws_size < oEND) return;

  u16* W1T = (u16*)(ws + oW1T);
  u16* W2T = (u16*)(ws + oW2T);
  u16* WQ0 = (u16*)(ws + oWQ0); u16* WQ1 = (u16*)(ws + oWQ1);
  u16* WO0 = (u16*)(ws + oWO0); u16* WO1 = (u16*)(ws + oWO1);
  float* X1 = (float*)(ws + oX1);
  u16* X1B  = (u16*)(ws + oX1B);

  int*   IDX0 = (int*)(ws + oMISC);
  int*   IDX1 = (int*)(ws + oMISC + 16384);
  int*   RNK0 = (int*)(ws + oMISC + 32768);
  int*   RNK1 = (int*)(ws + oMISC + 49152);
  int*   DST0 = (int*)(ws + oMISC + 65536);
  int*   DST1 = (int*)(ws + oMISC + 81920);
  float* G0   = (float*)(ws + oMISC + 98304);
  float* G1   = (float*)(ws + oMISC + 114688);
  int*   H0   = (int*)(ws + oMISC + 131072);
  int*   H1   = (int*)(ws + oMISC + 133120);
  int*   BS0  = (int*)(ws + oMISC + 135168);
  int*   BS1  = (int*)(ws + oMISC + 137216);
  int*   CNT0 = (int*)(ws + oMISC + 139264);
  int*   SLOT = (int*)(ws + oMISC + 139776);
  float* PTOK = (float*)(ws + oMISC + 262144);
  float* LSET = (float*)(ws + oMISC + 393216);

  u16* Qs0 = (u16*)(ws + oU1);           u16* Qs1 = (u16*)(ws + oU1 + PLB);
  u16* Ks0 = (u16*)(ws + oU1 + 2*PLB);   u16* Ks1 = (u16*)(ws + oU1 + 3*PLB);
  u16* Vs0 = (u16*)(ws + oU1 + 4*PLB);   u16* Vs1 = (u16*)(ws + oU1 + 5*PLB);
  u16* VTOK0 = (u16*)(ws + oU1 + 6*PLB); u16* VTOK1 = (u16*)(ws + oU1 + 7*PLB);  // V token planes
  float* ATTN = (float*)(ws + oU1);                          // 16 MB, after splits die
  u16* O0 = (u16*)(ws + oU1 + 16777216);
  u16* O1 = (u16*)(ws + oU1 + 16777216 + PLB);
  u16* HBUF = (u16*)(ws + oU1);                              // 80 MB, after ATTN/O/VTOK die

  u16* QT0 = (u16*)(ws + oU2);           u16* QT1 = (u16*)(ws + oU2 + PLB);      // Q token planes
  u16* KT0 = (u16*)(ws + oU2 + 2*PLB);   u16* KT1 = (u16*)(ws + oU2 + 3*PLB);    // K token planes
  u16* VT0 = (u16*)(ws + oU2 + 4*PLB);   u16* VT1 = (u16*)(ws + oU2 + 5*PLB);    // V (bh,dh,S) planes
  u16* XIN  = (u16*)(ws + oU2);                              // after attention
  u16* OUTE = (u16*)(ws + oU2 + 20971520);

  float* SCF = (float*)(ws + oU3);                           // 33.5 MB fp32
  u16* PH  = (u16*)(ws + oU3 + 33554432);
  u16* PL  = (u16*)(ws + oU3 + 50331648);

  hipMemsetAsync(ws + oMISC + 139776, 0xFF, (size_t)KE*KCAP*4, stream);

  // 2-plane f16 splits (residual plane scaled x4096)
  split2k<<<4096, 256, 0, stream>>>(q, Qs0, Qs1, (long)KN*KD/4);
  split2k<<<4096, 256, 0, stream>>>(k, Ks0, Ks1, (long)KN*KD/4);
  split2k<<<4096, 256, 0, stream>>>(v, Vs0, Vs1, (long)KN*KD/4);
  split2k<<<3072, 256, 0, stream>>>(inw, WQ0, WQ1, 786432);
  split2k<<<1024, 256, 0, stream>>>(outw, WO0, WO1, 262144);

  // FFN weight transposes to (N,K) f16 for NT GEMM
  trans_b<<<dim3(KDFF/32, KD/32, KE), dim3(32,8), 0, stream>>>(w1, W1T, KD, KDFF);
  trans_b<<<dim3(KD/32, KDFF/32, KE), dim3(32,8), 0, stream>>>(w2, W2T, KDFF, KD);

  // fused QKV projections (z=0:Q, 1:K, 2:V), f16 2-plane 3-term -> token layout
  // R6: 128x64-tile gemm64 (3 blocks/CU via 48KB LDS; no forced launch bounds)
  {
    GArgs ga{};
    ga.A0=Qs0; ga.A1=Qs1; ga.lda=KD; ga.sA=2*PLE;
    ga.B0=WQ0; ga.B1=WQ1; ga.ldb=KD; ga.sB=1048576;
    ga.bias=inb; ga.biasStride=KD;
    ga.o0=QT0; ga.o1=VTOK0; ga.outF=nullptr;
    ga.K=KD; ga.mode=7; ga.scale=1.f;
    gemm64<2><<<dim3(16, 32, 3), 256, 0, stream>>>(ga);
  }

  // V: token layout -> (bh, dh, S) for the PV GEMM (u16 passthrough, both planes)
  vtrans<<<dim3(KS/32, KD/32, KB), dim3(32,8), 0, stream>>>(VTOK0, VTOK1, VT0, VT1);

  // attention, chunked over bh (4 chunks of 32) — R3 structure
  for (int c = 0; c < KNCH; ++c){
    long hoff = (long)c * KCHB * KS * KDH;
    GArgs gs{};
    gs.A0=QT0; gs.A1=QT1; gs.lda=KD; gs.sA=0;
    gs.B0=KT0; gs.B1=KT1; gs.ldb=KD; gs.sB=0;
    gs.hbase = c*KCHB;
    gs.bias=nullptr; gs.biasStride=0; gs.outF=SCF; gs.o0=nullptr;
    gs.K=KDH; gs.mode=2; gs.scale=0.125f;
    gemm128<2><<<dim3(4, 4, KCHB), 256, 0, stream>>>(gs);

    softmax2<<<KCHB*KS, 64, 0, stream>>>(SCF, PH, PL);

    gemm_pv<<<dim3(4, KCHB), 256, 0, stream>>>(PH, PL, VT0+hoff, VT1+hoff,
                                               O0, O1, c*KCHB);
  }

  // out-projection -> ATTN fp32 (R6: gemm64)
  {
    GArgs go{};
    go.A0=O0; go.A1=O1; go.lda=KD; go.sA=0;
    go.B0=WO0; go.B1=WO1; go.ldb=KD; go.sB=0;
    go.bias=outb; go.biasStride=0; go.outF=ATTN; go.o0=nullptr;
    go.K=KD; go.mode=4; go.scale=1.f;
    gemm64<2><<<dim3(16, 32, 1), 256, 0, stream>>>(go);
  }

  // LN1 + router
  ln1_router<<<KN, 256, 0, stream>>>(q, ATTN, ln1w, ln1b, rw, X1, X1B,
                                     IDX0, IDX1, G0, G1, PTOK, LSET);
  // capacity-ordered routing
  scan1<<<64, 64, 0, stream>>>(IDX0, IDX1, RNK0, RNK1, H0, H1);
  scan2<<<1, 64, 0, stream>>>(H0, H1, BS0, BS1, CNT0);
  scan3<<<16, 256, 0, stream>>>(IDX0, IDX1, RNK0, RNK1, BS0, BS1, DST0, DST1, SLOT);
  aux_k<<<1, 1024, 0, stream>>>(CNT0, PTOK, LSET, out);
  gather_xin<<<KE*KCAP, 64, 0, stream>>>(SLOT, X1B, XIN);

  // expert FFN (plain f16, 1-plane)
  {
    GArgs f1{};
    f1.A0=XIN; f1.A1=nullptr; f1.lda=KD; f1.sA=(long)KCAP*KD;
    f1.B0=W1T; f1.B1=nullptr; f1.ldb=KD; f1.sB=(long)KDFF*KD;
    f1.bias=b1; f1.biasStride=KDFF; f1.outF=nullptr; f1.o0=HBUF;
    f1.K=KD; f1.mode=5; f1.scale=1.f;
    gemm128<1><<<dim3(KDFF/128, KCAP/128, KE), 256, 0, stream>>>(f1);

    GArgs f2{};
    f2.A0=HBUF; f2.A1=nullptr; f2.lda=KDFF; f2.sA=(long)KCAP*KDFF;
    f2.B0=W2T; f2.B1=nullptr; f2.ldb=KDFF; f2.sB=(long)KD*KDFF;
    f2.bias=b2; f2.biasStride=KD; f2.outF=nullptr; f2.o0=OUTE;
    f2.K=KDFF; f2.mode=6; f2.scale=1.f;
    gemm128<1><<<dim3(KD/128, KCAP/128, KE), 256, 0, stream>>>(f2);
  }

  // combine + LN2 -> output
  combine_ln2<<<KN, 256, 0, stream>>>(X1, OUTE, DST0, DST1, G0, G1, ln2w, ln2b, out);
}